// Round 3
// baseline (332.572 us; speedup 1.0000x reference)
//
#include <hip/hip_runtime.h>
#include <math.h>

// R2: MFMA bf16 GEMMs. R4: 4-deep edge unroll (49us, +17%).
// R5: agg1 FETCH_SIZE=154MB = 8 XCD x 19MB -> every XCD thrashes its 4MiB L2
// on the 20.5MB h1 table; gathers are L2 misses at 3.6 TB/s. Fix: head-sliced
// aggregation. wave = (node, head), gathers only that head's 128B slice.
// Per-head working set 2.56MB < 4MiB L2; head = blockIdx&7 rides the XCD
// round-robin so each XCD's L2 holds one head slice. agg2 same with 2 slices.

#define NEG_SLOPE 0.2f

using bf16x8 = __attribute__((ext_vector_type(8))) __bf16;
using f32x4  = __attribute__((ext_vector_type(4))) float;

// ---------- bf16 helpers (storage ushort, fp32 compute) ----------
__device__ __forceinline__ ushort f2bf(float f) {
    unsigned u = __float_as_uint(f);
    unsigned r = (u + 0x7FFFu + ((u >> 16) & 1u)) >> 16;   // RNE
    return (ushort)r;
}
__device__ __forceinline__ unsigned pack2(float a, float b) {
    return (unsigned)f2bf(a) | ((unsigned)f2bf(b) << 16);
}
__device__ __forceinline__ float bflo(unsigned u) { return __uint_as_float(u << 16); }
__device__ __forceinline__ float bfhi(unsigned u) { return __uint_as_float(u & 0xFFFF0000u); }

// ---------------- fp32 -> bf16 convert (n % 4 == 0) ----------------
__global__ __launch_bounds__(256) void cvt_bf16(const float* __restrict__ in,
                                                ushort* __restrict__ out, int n4) {
    int i = blockIdx.x * 256 + threadIdx.x;
    if (i >= n4) return;
    float4 v = ((const float4*)in)[i];
    uint2 o;
    o.x = pack2(v.x, v.y);
    o.y = pack2(v.z, v.w);
    ((uint2*)out)[i] = o;
}

// ---------------- MFMA GEMM: C[M,N] = A[M,K] * B[N,K]^T (all bf16, fp32 acc) ----
#define LDSB 40
__global__ __launch_bounds__(256) void gemm_mfma(const ushort* __restrict__ A,
                                                 const ushort* __restrict__ B,
                                                 ushort* __restrict__ C,
                                                 int M, int N, int K) {
    __shared__ ushort As[128 * LDSB];
    __shared__ ushort Bs[128 * LDSB];
    int t = threadIdx.x;
    int wave = t >> 6, lane = t & 63;
    int quad = lane >> 4, l16 = lane & 15;
    int m0 = blockIdx.x * 128;
    int n0 = blockIdx.y * 128;
    int wm = (wave & 1) * 64;
    int wn = (wave >> 1) * 64;
    int srow = t >> 1;
    int sseg = (t & 1) * 16;          // element offset (16 bf16 = 32 B)
    f32x4 acc[4][4] = {};             // [mi][nj]
    for (int k0 = 0; k0 < K; k0 += 32) {
        uint4 av0, av1, bv0, bv1;
        {
            int grow = m0 + srow;
            if (grow < M) {
                const uint4* gp = (const uint4*)(A + (size_t)grow * K + k0 + sseg);
                av0 = gp[0]; av1 = gp[1];
            } else {
                av0 = make_uint4(0, 0, 0, 0); av1 = av0;
            }
            const uint4* gq = (const uint4*)(B + (size_t)(n0 + srow) * K + k0 + sseg);
            bv0 = gq[0]; bv1 = gq[1];
        }
        __syncthreads();   // previous chunk's LDS readers done
        *(uint4*)&As[srow * LDSB + sseg]     = av0;
        *(uint4*)&As[srow * LDSB + sseg + 8] = av1;
        *(uint4*)&Bs[srow * LDSB + sseg]     = bv0;
        *(uint4*)&Bs[srow * LDSB + sseg + 8] = bv1;
        __syncthreads();
        bf16x8 af[4], bf[4];
#pragma unroll
        for (int i = 0; i < 4; ++i)
            af[i] = *(const bf16x8*)&As[(wm + i * 16 + l16) * LDSB + quad * 8];
#pragma unroll
        for (int j = 0; j < 4; ++j)
            bf[j] = *(const bf16x8*)&Bs[(wn + j * 16 + l16) * LDSB + quad * 8];
#pragma unroll
        for (int i = 0; i < 4; ++i)
#pragma unroll
            for (int j = 0; j < 4; ++j)
                acc[i][j] = __builtin_amdgcn_mfma_f32_16x16x32_bf16(
                    af[i], bf[j], acc[i][j], 0, 0, 0);
    }
    // epilogue: C/D layout col=lane&15, row=quad*4+reg
#pragma unroll
    for (int i = 0; i < 4; ++i) {
#pragma unroll
        for (int r = 0; r < 4; ++r) {
            int grow = m0 + wm + i * 16 + quad * 4 + r;
            if (grow < M) {
#pragma unroll
                for (int j = 0; j < 4; ++j) {
                    int gcol = n0 + wn + j * 16 + l16;
                    C[(size_t)grow * N + gcol] = f2bf(acc[i][j][r]);
                }
            }
        }
    }
}

// ---------------- Layer-1 attention scores: a1s/a1d [N,8], h1 bf16 ----------------
__global__ __launch_bounds__(256) void scores1(const ushort* __restrict__ h1,
                                               const float* __restrict__ att_s,
                                               const float* __restrict__ att_d,
                                               float* __restrict__ a1s,
                                               float* __restrict__ a1d, int N) {
    int node = blockIdx.x * 4 + (threadIdx.x >> 6);
    if (node >= N) return;
    int lane = threadIdx.x & 63;
    uint4 u = *(const uint4*)(h1 + (size_t)node * 512 + lane * 8);
    float h[8];
    h[0] = bflo(u.x); h[1] = bfhi(u.x);
    h[2] = bflo(u.y); h[3] = bfhi(u.y);
    h[4] = bflo(u.z); h[5] = bfhi(u.z);
    h[6] = bflo(u.w); h[7] = bfhi(u.w);
    const float4* sp = (const float4*)(att_s + lane * 8);
    const float4* dp = (const float4*)(att_d + lane * 8);
    float4 s0 = sp[0], s1 = sp[1], d0 = dp[0], d1 = dp[1];
    float ps = h[0] * s0.x + h[1] * s0.y + h[2] * s0.z + h[3] * s0.w +
               h[4] * s1.x + h[5] * s1.y + h[6] * s1.z + h[7] * s1.w;
    float pd = h[0] * d0.x + h[1] * d0.y + h[2] * d0.z + h[3] * d0.w +
               h[4] * d1.x + h[5] * d1.y + h[6] * d1.z + h[7] * d1.w;
#pragma unroll
    for (int off = 1; off < 8; off <<= 1) {
        ps += __shfl_xor(ps, off);
        pd += __shfl_xor(pd, off);
    }
    if ((lane & 7) == 0) {
        a1s[node * 8 + (lane >> 3)] = ps;
        a1d[node * 8 + (lane >> 3)] = pd;
    }
}

// ---------------- CSR build ----------------
__global__ void count_edges(const int* __restrict__ dst, int* cnt, int E) {
    int e = blockIdx.x * 256 + threadIdx.x;
    if (e < E) atomicAdd(&cnt[dst[e]], 1);
}

__global__ __launch_bounds__(1024) void scan_offsets(const int* cnt, int* row_start,
                                                     int* cursor, int N) {
    __shared__ int sm[1024];
    int t = threadIdx.x;
    int per = (N + 1023) / 1024;
    int beg = t * per;
    int end = beg + per; if (end > N) end = N;
    int sum = 0;
    for (int i = beg; i < end; ++i) sum += cnt[i];
    sm[t] = sum;
    __syncthreads();
    for (int off = 1; off < 1024; off <<= 1) {
        int add = (t >= off) ? sm[t - off] : 0;
        __syncthreads();
        sm[t] += add;
        __syncthreads();
    }
    int run = sm[t] - sum;
    for (int i = beg; i < end; ++i) {
        int c = cnt[i];
        row_start[i] = run;
        cursor[i] = run;
        run += c;
    }
    if (t == 1023) row_start[N] = run;
}

__global__ void fill_edges(const int* __restrict__ src, const int* __restrict__ dst,
                           int* cursor, int* __restrict__ srcs, int E) {
    int e = blockIdx.x * 256 + threadIdx.x;
    if (e < E) {
        int pos = atomicAdd(&cursor[dst[e]], 1);
        srcs[pos] = src[e];
    }
}

// -------- Layer-1 head-sliced softmax-aggregate + bias + relu --------
// wave = (node, head). head = blockIdx&7 -> XCD-affine: each XCD's L2 caches
// one head's 2.56MB column slice. 2x 32-lane halves, interleaved edges, 4-deep
// unroll per half = 8 gathers in flight. Lane covers 2 features (fbase).
__global__ __launch_bounds__(256) void agg1s(const ushort* __restrict__ h1,
                                             const float* __restrict__ a1s,
                                             const float* __restrict__ a1d,
                                             const int* __restrict__ row_start,
                                             const int* __restrict__ srcs,
                                             const float* __restrict__ b1,
                                             ushort* __restrict__ r1, int N) {
    int bid = blockIdx.x;
    int head = bid & 7;
    int node = (bid >> 3) * 4 + (threadIdx.x >> 6);
    if (node >= N) return;
    int lane = threadIdx.x & 63;
    int sub = lane & 31;
    int half = lane >> 5;
    int fbase = head * 64 + sub * 2;
    int pbeg = row_start[node], pend = row_start[node + 1];
    float ad = a1d[node * 8 + head];
    float es = a1s[node * 8 + head] + ad;
    es = es > 0.f ? es : NEG_SLOPE * es;
    float ex_self = __expf(es);
    unsigned uq = *(const unsigned*)(h1 + (size_t)node * 512 + fbase);
    float acc0 = 0.f, acc1 = 0.f, den = 0.f;
    int p = pbeg + half;
    for (; p + 6 < pend; p += 8) {
        int s0 = srcs[p];
        int s1 = srcs[p + 2];
        int s2 = srcs[p + 4];
        int s3 = srcs[p + 6];
        unsigned u0 = *(const unsigned*)(h1 + (size_t)s0 * 512 + fbase);
        unsigned u1 = *(const unsigned*)(h1 + (size_t)s1 * 512 + fbase);
        unsigned u2 = *(const unsigned*)(h1 + (size_t)s2 * 512 + fbase);
        unsigned u3 = *(const unsigned*)(h1 + (size_t)s3 * 512 + fbase);
        float as0 = a1s[s0 * 8 + head];
        float as1 = a1s[s1 * 8 + head];
        float as2 = a1s[s2 * 8 + head];
        float as3 = a1s[s3 * 8 + head];
        float e0 = as0 + ad; e0 = e0 > 0.f ? e0 : NEG_SLOPE * e0;
        float e1 = as1 + ad; e1 = e1 > 0.f ? e1 : NEG_SLOPE * e1;
        float e2 = as2 + ad; e2 = e2 > 0.f ? e2 : NEG_SLOPE * e2;
        float e3 = as3 + ad; e3 = e3 > 0.f ? e3 : NEG_SLOPE * e3;
        float x0 = __expf(e0), x1 = __expf(e1), x2 = __expf(e2), x3 = __expf(e3);
        den += (x0 + x1) + (x2 + x3);
        acc0 += x0 * bflo(u0); acc1 += x0 * bfhi(u0);
        acc0 += x1 * bflo(u1); acc1 += x1 * bfhi(u1);
        acc0 += x2 * bflo(u2); acc1 += x2 * bfhi(u2);
        acc0 += x3 * bflo(u3); acc1 += x3 * bfhi(u3);
    }
    for (; p < pend; p += 2) {
        int s = srcs[p];
        unsigned u = *(const unsigned*)(h1 + (size_t)s * 512 + fbase);
        float e = a1s[s * 8 + head] + ad;
        e = e > 0.f ? e : NEG_SLOPE * e;
        float ex = __expf(e);
        den += ex;
        acc0 += ex * bflo(u); acc1 += ex * bfhi(u);
    }
    // combine halves (each half summed its interleaved edge subset)
    acc0 += __shfl_xor(acc0, 32);
    acc1 += __shfl_xor(acc1, 32);
    den  += __shfl_xor(den, 32);
    den  += ex_self;
    acc0 += ex_self * bflo(uq);
    acc1 += ex_self * bfhi(uq);
    float rden = 1.0f / (den + 1e-16f);
    float o0 = fmaxf(acc0 * rden + b1[fbase], 0.f);
    float o1 = fmaxf(acc1 * rden + b1[fbase + 1], 0.f);
    if (half == 0)
        *(unsigned*)(r1 + (size_t)node * 512 + fbase) = pack2(o0, o1);
}

// ---------------- Layer-2 attention scores (H=1, C=128), h2 bf16 ----------------
__global__ __launch_bounds__(256) void scores2(const ushort* __restrict__ h2,
                                               const float* __restrict__ att_s,
                                               const float* __restrict__ att_d,
                                               float* __restrict__ a2s,
                                               float* __restrict__ a2d, int N) {
    int node = blockIdx.x * 4 + (threadIdx.x >> 6);
    if (node >= N) return;
    int lane = threadIdx.x & 63;
    unsigned u = *(const unsigned*)(h2 + (size_t)node * 128 + lane * 2);
    float h0 = bflo(u), h1v = bfhi(u);
    float2 s = *(const float2*)(att_s + lane * 2);
    float2 d = *(const float2*)(att_d + lane * 2);
    float ps = h0 * s.x + h1v * s.y;
    float pd = h0 * d.x + h1v * d.y;
#pragma unroll
    for (int off = 1; off < 64; off <<= 1) {
        ps += __shfl_xor(ps, off);
        pd += __shfl_xor(pd, off);
    }
    if (lane == 0) { a2s[node] = ps; a2d[node] = pd; }
}

// -------- Layer-2 feature-sliced aggregate: wave = (node, half-of-128) --------
// hh = blockIdx&1: XCD k (= bid%8) sees constant parity -> slice L2-resident
// (2.56MB). den recomputed per slice (cheap, score table is 80KB L2-hot).
__global__ __launch_bounds__(256) void agg2s(const ushort* __restrict__ h2,
                                             const float* __restrict__ a2s,
                                             const float* __restrict__ a2d,
                                             const int* __restrict__ row_start,
                                             const int* __restrict__ srcs,
                                             const float* __restrict__ b2,
                                             float* __restrict__ r2, int N) {
    int bid = blockIdx.x;
    int hh = bid & 1;
    int node = (bid >> 1) * 4 + (threadIdx.x >> 6);
    if (node >= N) return;
    int lane = threadIdx.x & 63;
    int sub = lane & 31;
    int half = lane >> 5;
    int fbase = hh * 64 + sub * 2;
    int pbeg = row_start[node], pend = row_start[node + 1];
    float ad = a2d[node];
    float es = a2s[node] + ad;
    es = es > 0.f ? es : NEG_SLOPE * es;
    float ex_self = __expf(es);
    unsigned uq = *(const unsigned*)(h2 + (size_t)node * 128 + fbase);
    float acc0 = 0.f, acc1 = 0.f, den = 0.f;
    int p = pbeg + half;
    for (; p + 6 < pend; p += 8) {
        int s0 = srcs[p];
        int s1 = srcs[p + 2];
        int s2 = srcs[p + 4];
        int s3 = srcs[p + 6];
        unsigned u0 = *(const unsigned*)(h2 + (size_t)s0 * 128 + fbase);
        unsigned u1 = *(const unsigned*)(h2 + (size_t)s1 * 128 + fbase);
        unsigned u2 = *(const unsigned*)(h2 + (size_t)s2 * 128 + fbase);
        unsigned u3 = *(const unsigned*)(h2 + (size_t)s3 * 128 + fbase);
        float as0 = a2s[s0];
        float as1 = a2s[s1];
        float as2 = a2s[s2];
        float as3 = a2s[s3];
        float e0 = as0 + ad; e0 = e0 > 0.f ? e0 : NEG_SLOPE * e0;
        float e1 = as1 + ad; e1 = e1 > 0.f ? e1 : NEG_SLOPE * e1;
        float e2 = as2 + ad; e2 = e2 > 0.f ? e2 : NEG_SLOPE * e2;
        float e3 = as3 + ad; e3 = e3 > 0.f ? e3 : NEG_SLOPE * e3;
        float x0 = __expf(e0), x1 = __expf(e1), x2 = __expf(e2), x3 = __expf(e3);
        den += (x0 + x1) + (x2 + x3);
        acc0 += x0 * bflo(u0); acc1 += x0 * bfhi(u0);
        acc0 += x1 * bflo(u1); acc1 += x1 * bfhi(u1);
        acc0 += x2 * bflo(u2); acc1 += x2 * bfhi(u2);
        acc0 += x3 * bflo(u3); acc1 += x3 * bfhi(u3);
    }
    for (; p < pend; p += 2) {
        int s = srcs[p];
        unsigned u = *(const unsigned*)(h2 + (size_t)s * 128 + fbase);
        float e = a2s[s] + ad;
        e = e > 0.f ? e : NEG_SLOPE * e;
        float ex = __expf(e);
        den += ex;
        acc0 += ex * bflo(u); acc1 += ex * bfhi(u);
    }
    acc0 += __shfl_xor(acc0, 32);
    acc1 += __shfl_xor(acc1, 32);
    den  += __shfl_xor(den, 32);
    den  += ex_self;
    acc0 += ex_self * bflo(uq);
    acc1 += ex_self * bfhi(uq);
    float rden = 1.0f / (den + 1e-16f);
    float o0 = fmaxf(acc0 * rden + b2[fbase], 0.f);
    float o1 = fmaxf(acc1 * rden + b2[fbase + 1], 0.f);
    if (half == 0) {
        float2 ov; ov.x = o0; ov.y = o1;
        *(float2*)(r2 + (size_t)node * 128 + fbase) = ov;
    }
}

// ---------------- Attention pooling ----------------
__global__ __launch_bounds__(256) void pool_kernel(const float* __restrict__ r2,
                                                   const int* __restrict__ batch,
                                                   const float* __restrict__ w_attn,
                                                   const float* __restrict__ b_attn,
                                                   const float* __restrict__ w_mask,
                                                   const float* __restrict__ b_mask,
                                                   float* pooled, int N) {
    int node = blockIdx.x * 4 + (threadIdx.x >> 6);
    if (node >= N) return;
    int lane = threadIdx.x & 63;
    float2 h = *(const float2*)(r2 + (size_t)node * 128 + lane * 2);
    float2 wa = *(const float2*)(w_attn + lane * 2);
    float2 wm = *(const float2*)(w_mask + lane * 2);
    float pa = h.x * wa.x + h.y * wa.y;
    float pm = h.x * wm.x + h.y * wm.y;
#pragma unroll
    for (int off = 1; off < 64; off <<= 1) {
        pa += __shfl_xor(pa, off);
        pm += __shfl_xor(pm, off);
    }
    float attn = pa + b_attn[0];
    float mask = 1.0f / (1.0f + __expf(-(pm + b_mask[0])));
    float w = attn * mask;
    int g = batch[node];
    atomicAdd(&pooled[g * 128 + lane * 2], h.x * w);
    atomicAdd(&pooled[g * 128 + lane * 2 + 1], h.y * w);
}

// ---------------- Final tiny GEMM: out[256,2] ----------------
__global__ void final_kernel(const float* __restrict__ pooled,
                             const float* __restrict__ W_out,
                             const float* __restrict__ b_out,
                             float* __restrict__ out) {
    int tid = blockIdx.x * 256 + threadIdx.x;
    if (tid >= 512) return;
    int g = tid >> 1, o = tid & 1;
    const float* p = pooled + g * 128;
    const float* w = W_out + o * 128;
    float s = 0.f;
#pragma unroll 4
    for (int f = 0; f < 128; ++f) s += p[f] * w[f];
    out[tid] = s + b_out[o];
}

extern "C" void kernel_launch(void* const* d_in, const int* in_sizes, int n_in,
                              void* d_out, int out_size, void* d_ws, size_t ws_size,
                              hipStream_t stream) {
    const float* x        = (const float*)d_in[0];
    const int* edge_index = (const int*)d_in[1];
    const int* batch      = (const int*)d_in[2];
    const float* W1       = (const float*)d_in[3];
    const float* att_src1 = (const float*)d_in[4];
    const float* att_dst1 = (const float*)d_in[5];
    const float* b1       = (const float*)d_in[6];
    const float* W2       = (const float*)d_in[7];
    const float* att_src2 = (const float*)d_in[8];
    const float* att_dst2 = (const float*)d_in[9];
    const float* b2       = (const float*)d_in[10];
    const float* w_attn   = (const float*)d_in[11];
    const float* b_attn   = (const float*)d_in[12];
    const float* w_mask   = (const float*)d_in[13];
    const float* b_mask   = (const float*)d_in[14];
    const float* W_out    = (const float*)d_in[15];
    const float* b_out    = (const float*)d_in[16];
    float* out = (float*)d_out;

    int N = in_sizes[0] / 128;
    int E = in_sizes[1] / 2;
    const int* esrc = edge_index;
    const int* edst = edge_index + E;

    char* ws = (char*)d_ws;
    size_t off = 0;
    auto alloc = [&](size_t bytes) {
        void* p = ws + off;
        off = (off + bytes + 255) & ~(size_t)255;
        return p;
    };
    ushort* h1       = (ushort*)alloc((size_t)N * 512 * 2);   // bf16
    ushort* r1       = (ushort*)alloc((size_t)N * 512 * 2);   // bf16
    ushort* h2       = (ushort*)alloc((size_t)N * 128 * 2);   // bf16
    float*  r2       = (float*)alloc((size_t)N * 128 * 4);
    ushort* xb       = (ushort*)alloc((size_t)N * 128 * 2);   // bf16 x
    ushort* w1b      = (ushort*)alloc((size_t)512 * 128 * 2);
    ushort* w2b      = (ushort*)alloc((size_t)128 * 512 * 2);
    float*  a1s      = (float*)alloc((size_t)N * 8 * 4);
    float*  a1d      = (float*)alloc((size_t)N * 8 * 4);
    float*  a2s      = (float*)alloc((size_t)N * 4);
    float*  a2d      = (float*)alloc((size_t)N * 4);
    int*    row_start= (int*)alloc((size_t)(N + 1) * 4);
    int*    cursor   = (int*)alloc((size_t)N * 4);
    int*    srcs     = (int*)alloc((size_t)E * 4);
    float*  pooled   = (float*)alloc((size_t)256 * 128 * 4);

    hipMemsetAsync(cursor, 0, (size_t)N * 4, stream);
    hipMemsetAsync(pooled, 0, 256 * 128 * 4, stream);

    dim3 b256(256);
    // converts
    int nx4 = N * 128 / 4;
    cvt_bf16<<<(nx4 + 255) / 256, b256, 0, stream>>>(x, xb, nx4);
    cvt_bf16<<<(512 * 128 / 4 + 255) / 256, b256, 0, stream>>>(W1, w1b, 512 * 128 / 4);
    cvt_bf16<<<(128 * 512 / 4 + 255) / 256, b256, 0, stream>>>(W2, w2b, 128 * 512 / 4);
    // CSR build (independent of GEMM1)
    count_edges<<<(E + 255) / 256, b256, 0, stream>>>(edst, cursor, E);
    scan_offsets<<<1, 1024, 0, stream>>>(cursor, row_start, cursor, N);
    fill_edges<<<(E + 255) / 256, b256, 0, stream>>>(esrc, edst, cursor, srcs, E);
    // layer 1
    gemm_mfma<<<dim3((N + 127) / 128, 512 / 128), b256, 0, stream>>>(xb, w1b, h1, N, 512, 128);
    scores1<<<(N + 3) / 4, b256, 0, stream>>>(h1, att_src1, att_dst1, a1s, a1d, N);
    agg1s<<<((N + 3) / 4) * 8, b256, 0, stream>>>(h1, a1s, a1d, row_start, srcs, b1, r1, N);
    // layer 2
    gemm_mfma<<<dim3((N + 127) / 128, 128 / 128), b256, 0, stream>>>(r1, w2b, h2, N, 128, 512);
    scores2<<<(N + 3) / 4, b256, 0, stream>>>(h2, att_src2, att_dst2, a2s, a2d, N);
    agg2s<<<((N + 3) / 4) * 2, b256, 0, stream>>>(h2, a2s, a2d, row_start, srcs, b2, r2, N);
    // pooling + head
    pool_kernel<<<(N + 3) / 4, b256, 0, stream>>>(r2, batch, w_attn, b_attn, w_mask,
                                                  b_mask, pooled, N);
    final_kernel<<<2, b256, 0, stream>>>(pooled, W_out, b_out, out);
}

// Round 4
// 325.824 us; speedup vs baseline: 1.0207x; 1.0207x over previous
//
#include <hip/hip_runtime.h>
#include <math.h>

// R2: MFMA bf16 GEMMs. R4: 4-deep edge unroll (agg1 49us).
// R5: head-sliced agg -> FETCH 154->23MB (L2-resident works!) but 4B/lane
// gathers + 32x-replicated exp made it VALU-bound (86% VALU, 81us).
// R6: keep slicing, restore instruction density: wave=(node,head), 8 edge-
// groups x 8 lanes, each lane gathers 16B (8 feats) of the 128B head slice.
// exp replicated only 8x (as R4); shfl_xor(8/16/32) folds edge-groups.

#define NEG_SLOPE 0.2f

using bf16x8 = __attribute__((ext_vector_type(8))) __bf16;
using f32x4  = __attribute__((ext_vector_type(4))) float;

// ---------- bf16 helpers (storage ushort, fp32 compute) ----------
__device__ __forceinline__ ushort f2bf(float f) {
    unsigned u = __float_as_uint(f);
    unsigned r = (u + 0x7FFFu + ((u >> 16) & 1u)) >> 16;   // RNE
    return (ushort)r;
}
__device__ __forceinline__ unsigned pack2(float a, float b) {
    return (unsigned)f2bf(a) | ((unsigned)f2bf(b) << 16);
}
__device__ __forceinline__ float bflo(unsigned u) { return __uint_as_float(u << 16); }
__device__ __forceinline__ float bfhi(unsigned u) { return __uint_as_float(u & 0xFFFF0000u); }
__device__ __forceinline__ void unpack8(uint4 u, float* f) {
    f[0] = bflo(u.x); f[1] = bfhi(u.x);
    f[2] = bflo(u.y); f[3] = bfhi(u.y);
    f[4] = bflo(u.z); f[5] = bfhi(u.z);
    f[6] = bflo(u.w); f[7] = bfhi(u.w);
}

// ---------------- fp32 -> bf16 convert (n % 4 == 0) ----------------
__global__ __launch_bounds__(256) void cvt_bf16(const float* __restrict__ in,
                                                ushort* __restrict__ out, int n4) {
    int i = blockIdx.x * 256 + threadIdx.x;
    if (i >= n4) return;
    float4 v = ((const float4*)in)[i];
    uint2 o;
    o.x = pack2(v.x, v.y);
    o.y = pack2(v.z, v.w);
    ((uint2*)out)[i] = o;
}

// ---------------- MFMA GEMM: C[M,N] = A[M,K] * B[N,K]^T (all bf16, fp32 acc) ----
#define LDSB 40
__global__ __launch_bounds__(256) void gemm_mfma(const ushort* __restrict__ A,
                                                 const ushort* __restrict__ B,
                                                 ushort* __restrict__ C,
                                                 int M, int N, int K) {
    __shared__ ushort As[128 * LDSB];
    __shared__ ushort Bs[128 * LDSB];
    int t = threadIdx.x;
    int wave = t >> 6, lane = t & 63;
    int quad = lane >> 4, l16 = lane & 15;
    int m0 = blockIdx.x * 128;
    int n0 = blockIdx.y * 128;
    int wm = (wave & 1) * 64;
    int wn = (wave >> 1) * 64;
    int srow = t >> 1;
    int sseg = (t & 1) * 16;          // element offset (16 bf16 = 32 B)
    f32x4 acc[4][4] = {};             // [mi][nj]
    for (int k0 = 0; k0 < K; k0 += 32) {
        uint4 av0, av1, bv0, bv1;
        {
            int grow = m0 + srow;
            if (grow < M) {
                const uint4* gp = (const uint4*)(A + (size_t)grow * K + k0 + sseg);
                av0 = gp[0]; av1 = gp[1];
            } else {
                av0 = make_uint4(0, 0, 0, 0); av1 = av0;
            }
            const uint4* gq = (const uint4*)(B + (size_t)(n0 + srow) * K + k0 + sseg);
            bv0 = gq[0]; bv1 = gq[1];
        }
        __syncthreads();   // previous chunk's LDS readers done
        *(uint4*)&As[srow * LDSB + sseg]     = av0;
        *(uint4*)&As[srow * LDSB + sseg + 8] = av1;
        *(uint4*)&Bs[srow * LDSB + sseg]     = bv0;
        *(uint4*)&Bs[srow * LDSB + sseg + 8] = bv1;
        __syncthreads();
        bf16x8 af[4], bf[4];
#pragma unroll
        for (int i = 0; i < 4; ++i)
            af[i] = *(const bf16x8*)&As[(wm + i * 16 + l16) * LDSB + quad * 8];
#pragma unroll
        for (int j = 0; j < 4; ++j)
            bf[j] = *(const bf16x8*)&Bs[(wn + j * 16 + l16) * LDSB + quad * 8];
#pragma unroll
        for (int i = 0; i < 4; ++i)
#pragma unroll
            for (int j = 0; j < 4; ++j)
                acc[i][j] = __builtin_amdgcn_mfma_f32_16x16x32_bf16(
                    af[i], bf[j], acc[i][j], 0, 0, 0);
    }
    // epilogue: C/D layout col=lane&15, row=quad*4+reg
#pragma unroll
    for (int i = 0; i < 4; ++i) {
#pragma unroll
        for (int r = 0; r < 4; ++r) {
            int grow = m0 + wm + i * 16 + quad * 4 + r;
            if (grow < M) {
#pragma unroll
                for (int j = 0; j < 4; ++j) {
                    int gcol = n0 + wn + j * 16 + l16;
                    C[(size_t)grow * N + gcol] = f2bf(acc[i][j][r]);
                }
            }
        }
    }
}

// ---------------- Layer-1 attention scores: a1s/a1d [N,8], h1 bf16 ----------------
__global__ __launch_bounds__(256) void scores1(const ushort* __restrict__ h1,
                                               const float* __restrict__ att_s,
                                               const float* __restrict__ att_d,
                                               float* __restrict__ a1s,
                                               float* __restrict__ a1d, int N) {
    int node = blockIdx.x * 4 + (threadIdx.x >> 6);
    if (node >= N) return;
    int lane = threadIdx.x & 63;
    uint4 u = *(const uint4*)(h1 + (size_t)node * 512 + lane * 8);
    float h[8];
    unpack8(u, h);
    const float4* sp = (const float4*)(att_s + lane * 8);
    const float4* dp = (const float4*)(att_d + lane * 8);
    float4 s0 = sp[0], s1 = sp[1], d0 = dp[0], d1 = dp[1];
    float ps = h[0] * s0.x + h[1] * s0.y + h[2] * s0.z + h[3] * s0.w +
               h[4] * s1.x + h[5] * s1.y + h[6] * s1.z + h[7] * s1.w;
    float pd = h[0] * d0.x + h[1] * d0.y + h[2] * d0.z + h[3] * d0.w +
               h[4] * d1.x + h[5] * d1.y + h[6] * d1.z + h[7] * d1.w;
#pragma unroll
    for (int off = 1; off < 8; off <<= 1) {
        ps += __shfl_xor(ps, off);
        pd += __shfl_xor(pd, off);
    }
    if ((lane & 7) == 0) {
        a1s[node * 8 + (lane >> 3)] = ps;
        a1d[node * 8 + (lane >> 3)] = pd;
    }
}

// ---------------- CSR build ----------------
__global__ void count_edges(const int* __restrict__ dst, int* cnt, int E) {
    int e = blockIdx.x * 256 + threadIdx.x;
    if (e < E) atomicAdd(&cnt[dst[e]], 1);
}

__global__ __launch_bounds__(1024) void scan_offsets(const int* cnt, int* row_start,
                                                     int* cursor, int N) {
    __shared__ int sm[1024];
    int t = threadIdx.x;
    int per = (N + 1023) / 1024;
    int beg = t * per;
    int end = beg + per; if (end > N) end = N;
    int sum = 0;
    for (int i = beg; i < end; ++i) sum += cnt[i];
    sm[t] = sum;
    __syncthreads();
    for (int off = 1; off < 1024; off <<= 1) {
        int add = (t >= off) ? sm[t - off] : 0;
        __syncthreads();
        sm[t] += add;
        __syncthreads();
    }
    int run = sm[t] - sum;
    for (int i = beg; i < end; ++i) {
        int c = cnt[i];
        row_start[i] = run;
        cursor[i] = run;
        run += c;
    }
    if (t == 1023) row_start[N] = run;
}

__global__ void fill_edges(const int* __restrict__ src, const int* __restrict__ dst,
                           int* cursor, int* __restrict__ srcs, int E) {
    int e = blockIdx.x * 256 + threadIdx.x;
    if (e < E) {
        int pos = atomicAdd(&cursor[dst[e]], 1);
        srcs[pos] = src[e];
    }
}

// -------- Layer-1 head-sliced aggregate, edge-group structure --------
// wave = (node, head). head = blockIdx&7 (XCD-affine, 2.56MB slice L2-resident).
// 8 groups x 8 lanes: group g handles edges p+g; lane gathers 16B (8 feats).
// exp replicated 8x per edge (not 32x); shfl_xor(8/16/32) folds groups.
__global__ __launch_bounds__(256) void agg1g(const ushort* __restrict__ h1,
                                             const float* __restrict__ a1s,
                                             const float* __restrict__ a1d,
                                             const int* __restrict__ row_start,
                                             const int* __restrict__ srcs,
                                             const float* __restrict__ b1,
                                             ushort* __restrict__ r1, int N) {
    int bid = blockIdx.x;
    int head = bid & 7;
    int node = (bid >> 3) * 4 + (threadIdx.x >> 6);
    if (node >= N) return;
    int lane = threadIdx.x & 63;
    int g = lane >> 3;          // edge group 0..7
    int fl = lane & 7;          // feature chunk 0..7
    int fbase = head * 64 + fl * 8;
    int pbeg = row_start[node], pend = row_start[node + 1];
    float ad = a1d[node * 8 + head];
    float acc[8] = {};
    float den = 0.f;
    for (int p = pbeg; p < pend; p += 8) {
        int pg = p + g;
        bool ok = pg < pend;
        int s = srcs[ok ? pg : pbeg];
        uint4 u = *(const uint4*)(h1 + (size_t)s * 512 + fbase);
        float e = a1s[s * 8 + head] + ad;
        e = e > 0.f ? e : NEG_SLOPE * e;
        float x = ok ? __expf(e) : 0.f;
        den += x;
        float v[8];
        unpack8(u, v);
#pragma unroll
        for (int j = 0; j < 8; ++j) acc[j] += x * v[j];
    }
    // fold the 8 edge-groups (xor over lane bits 3..5)
#pragma unroll
    for (int j = 0; j < 8; ++j) {
        acc[j] += __shfl_xor(acc[j], 8);
        acc[j] += __shfl_xor(acc[j], 16);
        acc[j] += __shfl_xor(acc[j], 32);
    }
    den += __shfl_xor(den, 8);
    den += __shfl_xor(den, 16);
    den += __shfl_xor(den, 32);
    // self edge (uniform across groups)
    float es = a1s[node * 8 + head] + ad;
    es = es > 0.f ? es : NEG_SLOPE * es;
    float ex_self = __expf(es);
    den += ex_self;
    float q[8];
    unpack8(*(const uint4*)(h1 + (size_t)node * 512 + fbase), q);
#pragma unroll
    for (int j = 0; j < 8; ++j) acc[j] += ex_self * q[j];
    if (g == 0) {
        float rden = 1.0f / (den + 1e-16f);
        const float4* bp = (const float4*)(b1 + fbase);
        float4 b0 = bp[0], b1v = bp[1];
        float o[8];
        o[0] = fmaxf(acc[0] * rden + b0.x, 0.f);
        o[1] = fmaxf(acc[1] * rden + b0.y, 0.f);
        o[2] = fmaxf(acc[2] * rden + b0.z, 0.f);
        o[3] = fmaxf(acc[3] * rden + b0.w, 0.f);
        o[4] = fmaxf(acc[4] * rden + b1v.x, 0.f);
        o[5] = fmaxf(acc[5] * rden + b1v.y, 0.f);
        o[6] = fmaxf(acc[6] * rden + b1v.z, 0.f);
        o[7] = fmaxf(acc[7] * rden + b1v.w, 0.f);
        uint4 ov;
        ov.x = pack2(o[0], o[1]); ov.y = pack2(o[2], o[3]);
        ov.z = pack2(o[4], o[5]); ov.w = pack2(o[6], o[7]);
        *(uint4*)(r1 + (size_t)node * 512 + fbase) = ov;
    }
}

// ---------------- Layer-2 attention scores (H=1, C=128), h2 bf16 ----------------
__global__ __launch_bounds__(256) void scores2(const ushort* __restrict__ h2,
                                               const float* __restrict__ att_s,
                                               const float* __restrict__ att_d,
                                               float* __restrict__ a2s,
                                               float* __restrict__ a2d, int N) {
    int node = blockIdx.x * 4 + (threadIdx.x >> 6);
    if (node >= N) return;
    int lane = threadIdx.x & 63;
    unsigned u = *(const unsigned*)(h2 + (size_t)node * 128 + lane * 2);
    float h0 = bflo(u), h1v = bfhi(u);
    float2 s = *(const float2*)(att_s + lane * 2);
    float2 d = *(const float2*)(att_d + lane * 2);
    float ps = h0 * s.x + h1v * s.y;
    float pd = h0 * d.x + h1v * d.y;
#pragma unroll
    for (int off = 1; off < 64; off <<= 1) {
        ps += __shfl_xor(ps, off);
        pd += __shfl_xor(pd, off);
    }
    if (lane == 0) { a2s[node] = ps; a2d[node] = pd; }
}

// -------- Layer-2 parity-sliced aggregate, edge-group structure --------
// wave = (node, half). hh = blockIdx&1 (XCD parity-affine, 2.56MB slice).
__global__ __launch_bounds__(256) void agg2g(const ushort* __restrict__ h2,
                                             const float* __restrict__ a2s,
                                             const float* __restrict__ a2d,
                                             const int* __restrict__ row_start,
                                             const int* __restrict__ srcs,
                                             const float* __restrict__ b2,
                                             float* __restrict__ r2, int N) {
    int bid = blockIdx.x;
    int hh = bid & 1;
    int node = (bid >> 1) * 4 + (threadIdx.x >> 6);
    if (node >= N) return;
    int lane = threadIdx.x & 63;
    int g = lane >> 3;
    int fl = lane & 7;
    int fbase = hh * 64 + fl * 8;
    int pbeg = row_start[node], pend = row_start[node + 1];
    float ad = a2d[node];
    float acc[8] = {};
    float den = 0.f;
    for (int p = pbeg; p < pend; p += 8) {
        int pg = p + g;
        bool ok = pg < pend;
        int s = srcs[ok ? pg : pbeg];
        uint4 u = *(const uint4*)(h2 + (size_t)s * 128 + fbase);
        float e = a2s[s] + ad;
        e = e > 0.f ? e : NEG_SLOPE * e;
        float x = ok ? __expf(e) : 0.f;
        den += x;
        float v[8];
        unpack8(u, v);
#pragma unroll
        for (int j = 0; j < 8; ++j) acc[j] += x * v[j];
    }
#pragma unroll
    for (int j = 0; j < 8; ++j) {
        acc[j] += __shfl_xor(acc[j], 8);
        acc[j] += __shfl_xor(acc[j], 16);
        acc[j] += __shfl_xor(acc[j], 32);
    }
    den += __shfl_xor(den, 8);
    den += __shfl_xor(den, 16);
    den += __shfl_xor(den, 32);
    float es = a2s[node] + ad;
    es = es > 0.f ? es : NEG_SLOPE * es;
    float ex_self = __expf(es);
    den += ex_self;
    float q[8];
    unpack8(*(const uint4*)(h2 + (size_t)node * 128 + fbase), q);
#pragma unroll
    for (int j = 0; j < 8; ++j) acc[j] += ex_self * q[j];
    if (g == 0) {
        float rden = 1.0f / (den + 1e-16f);
        const float4* bp = (const float4*)(b2 + fbase);
        float4 b0 = bp[0], b1v = bp[1];
        float4 o0, o1;
        o0.x = fmaxf(acc[0] * rden + b0.x, 0.f);
        o0.y = fmaxf(acc[1] * rden + b0.y, 0.f);
        o0.z = fmaxf(acc[2] * rden + b0.z, 0.f);
        o0.w = fmaxf(acc[3] * rden + b0.w, 0.f);
        o1.x = fmaxf(acc[4] * rden + b1v.x, 0.f);
        o1.y = fmaxf(acc[5] * rden + b1v.y, 0.f);
        o1.z = fmaxf(acc[6] * rden + b1v.z, 0.f);
        o1.w = fmaxf(acc[7] * rden + b1v.w, 0.f);
        *(float4*)(r2 + (size_t)node * 128 + fbase) = o0;
        *(float4*)(r2 + (size_t)node * 128 + fbase + 4) = o1;
    }
}

// ---------------- Attention pooling ----------------
__global__ __launch_bounds__(256) void pool_kernel(const float* __restrict__ r2,
                                                   const int* __restrict__ batch,
                                                   const float* __restrict__ w_attn,
                                                   const float* __restrict__ b_attn,
                                                   const float* __restrict__ w_mask,
                                                   const float* __restrict__ b_mask,
                                                   float* pooled, int N) {
    int node = blockIdx.x * 4 + (threadIdx.x >> 6);
    if (node >= N) return;
    int lane = threadIdx.x & 63;
    float2 h = *(const float2*)(r2 + (size_t)node * 128 + lane * 2);
    float2 wa = *(const float2*)(w_attn + lane * 2);
    float2 wm = *(const float2*)(w_mask + lane * 2);
    float pa = h.x * wa.x + h.y * wa.y;
    float pm = h.x * wm.x + h.y * wm.y;
#pragma unroll
    for (int off = 1; off < 64; off <<= 1) {
        pa += __shfl_xor(pa, off);
        pm += __shfl_xor(pm, off);
    }
    float attn = pa + b_attn[0];
    float mask = 1.0f / (1.0f + __expf(-(pm + b_mask[0])));
    float w = attn * mask;
    int g = batch[node];
    atomicAdd(&pooled[g * 128 + lane * 2], h.x * w);
    atomicAdd(&pooled[g * 128 + lane * 2 + 1], h.y * w);
}

// ---------------- Final tiny GEMM: out[256,2] ----------------
__global__ void final_kernel(const float* __restrict__ pooled,
                             const float* __restrict__ W_out,
                             const float* __restrict__ b_out,
                             float* __restrict__ out) {
    int tid = blockIdx.x * 256 + threadIdx.x;
    if (tid >= 512) return;
    int g = tid >> 1, o = tid & 1;
    const float* p = pooled + g * 128;
    const float* w = W_out + o * 128;
    float s = 0.f;
#pragma unroll 4
    for (int f = 0; f < 128; ++f) s += p[f] * w[f];
    out[tid] = s + b_out[o];
}

extern "C" void kernel_launch(void* const* d_in, const int* in_sizes, int n_in,
                              void* d_out, int out_size, void* d_ws, size_t ws_size,
                              hipStream_t stream) {
    const float* x        = (const float*)d_in[0];
    const int* edge_index = (const int*)d_in[1];
    const int* batch      = (const int*)d_in[2];
    const float* W1       = (const float*)d_in[3];
    const float* att_src1 = (const float*)d_in[4];
    const float* att_dst1 = (const float*)d_in[5];
    const float* b1       = (const float*)d_in[6];
    const float* W2       = (const float*)d_in[7];
    const float* att_src2 = (const float*)d_in[8];
    const float* att_dst2 = (const float*)d_in[9];
    const float* b2       = (const float*)d_in[10];
    const float* w_attn   = (const float*)d_in[11];
    const float* b_attn   = (const float*)d_in[12];
    const float* w_mask   = (const float*)d_in[13];
    const float* b_mask   = (const float*)d_in[14];
    const float* W_out    = (const float*)d_in[15];
    const float* b_out    = (const float*)d_in[16];
    float* out = (float*)d_out;

    int N = in_sizes[0] / 128;
    int E = in_sizes[1] / 2;
    const int* esrc = edge_index;
    const int* edst = edge_index + E;

    char* ws = (char*)d_ws;
    size_t off = 0;
    auto alloc = [&](size_t bytes) {
        void* p = ws + off;
        off = (off + bytes + 255) & ~(size_t)255;
        return p;
    };
    ushort* h1       = (ushort*)alloc((size_t)N * 512 * 2);   // bf16
    ushort* r1       = (ushort*)alloc((size_t)N * 512 * 2);   // bf16
    ushort* h2       = (ushort*)alloc((size_t)N * 128 * 2);   // bf16
    float*  r2       = (float*)alloc((size_t)N * 128 * 4);
    ushort* xb       = (ushort*)alloc((size_t)N * 128 * 2);   // bf16 x
    ushort* w1b      = (ushort*)alloc((size_t)512 * 128 * 2);
    ushort* w2b      = (ushort*)alloc((size_t)128 * 512 * 2);
    float*  a1s      = (float*)alloc((size_t)N * 8 * 4);
    float*  a1d      = (float*)alloc((size_t)N * 8 * 4);
    float*  a2s      = (float*)alloc((size_t)N * 4);
    float*  a2d      = (float*)alloc((size_t)N * 4);
    int*    row_start= (int*)alloc((size_t)(N + 1) * 4);
    int*    cursor   = (int*)alloc((size_t)N * 4);
    int*    srcs     = (int*)alloc((size_t)E * 4);
    float*  pooled   = (float*)alloc((size_t)256 * 128 * 4);

    hipMemsetAsync(cursor, 0, (size_t)N * 4, stream);
    hipMemsetAsync(pooled, 0, 256 * 128 * 4, stream);

    dim3 b256(256);
    // converts
    int nx4 = N * 128 / 4;
    cvt_bf16<<<(nx4 + 255) / 256, b256, 0, stream>>>(x, xb, nx4);
    cvt_bf16<<<(512 * 128 / 4 + 255) / 256, b256, 0, stream>>>(W1, w1b, 512 * 128 / 4);
    cvt_bf16<<<(128 * 512 / 4 + 255) / 256, b256, 0, stream>>>(W2, w2b, 128 * 512 / 4);
    // CSR build (independent of GEMM1)
    count_edges<<<(E + 255) / 256, b256, 0, stream>>>(edst, cursor, E);
    scan_offsets<<<1, 1024, 0, stream>>>(cursor, row_start, cursor, N);
    fill_edges<<<(E + 255) / 256, b256, 0, stream>>>(esrc, edst, cursor, srcs, E);
    // layer 1
    gemm_mfma<<<dim3((N + 127) / 128, 512 / 128), b256, 0, stream>>>(xb, w1b, h1, N, 512, 128);
    scores1<<<(N + 3) / 4, b256, 0, stream>>>(h1, att_src1, att_dst1, a1s, a1d, N);
    agg1g<<<((N + 3) / 4) * 8, b256, 0, stream>>>(h1, a1s, a1d, row_start, srcs, b1, r1, N);
    // layer 2
    gemm_mfma<<<dim3((N + 127) / 128, 128 / 128), b256, 0, stream>>>(r1, w2b, h2, N, 128, 512);
    scores2<<<(N + 3) / 4, b256, 0, stream>>>(h2, att_src2, att_dst2, a2s, a2d, N);
    agg2g<<<((N + 3) / 4) * 2, b256, 0, stream>>>(h2, a2s, a2d, row_start, srcs, b2, r2, N);
    // pooling + head
    pool_kernel<<<(N + 3) / 4, b256, 0, stream>>>(r2, batch, w_attn, b_attn, w_mask,
                                                  b_mask, pooled, N);
    final_kernel<<<2, b256, 0, stream>>>(pooled, W_out, b_out, out);
}

// Round 6
// 294.144 us; speedup vs baseline: 1.1306x; 1.1077x over previous
//
#include <hip/hip_runtime.h>
#include <math.h>

// R2: MFMA bf16 GEMMs. R4: 4-deep unroll agg1=49us. R5/R6: L2-resident head
// slicing — FETCH 154->23MB but ~80us (8x waves + chain latency ate the win).
// R7: revert agg1 to R4 unsliced structure w/ masked 8-deep unroll; fuse
// scores1/2 into gemm epilogues (scores from fp32 acc, no h re-read); single
// convert kernel; single memset. 15 -> 11 launches.
// R8: unchanged resubmit — R7 bench was an infra failure (container died
// twice); need R7's counters before the next edit.

#define NEG_SLOPE 0.2f

using bf16x8 = __attribute__((ext_vector_type(8))) __bf16;
using f32x4  = __attribute__((ext_vector_type(4))) float;

// ---------- bf16 helpers (storage ushort, fp32 compute) ----------
__device__ __forceinline__ ushort f2bf(float f) {
    unsigned u = __float_as_uint(f);
    unsigned r = (u + 0x7FFFu + ((u >> 16) & 1u)) >> 16;   // RNE
    return (ushort)r;
}
__device__ __forceinline__ unsigned pack2(float a, float b) {
    return (unsigned)f2bf(a) | ((unsigned)f2bf(b) << 16);
}
__device__ __forceinline__ float bflo(unsigned u) { return __uint_as_float(u << 16); }
__device__ __forceinline__ float bfhi(unsigned u) { return __uint_as_float(u & 0xFFFF0000u); }
__device__ __forceinline__ void unpack8(uint4 u, float* f) {
    f[0] = bflo(u.x); f[1] = bfhi(u.x);
    f[2] = bflo(u.y); f[3] = bfhi(u.y);
    f[4] = bflo(u.z); f[5] = bfhi(u.z);
    f[6] = bflo(u.w); f[7] = bfhi(u.w);
}
__device__ __forceinline__ void unpack4(uint2 u, float* f) {
    f[0] = bflo(u.x); f[1] = bfhi(u.x);
    f[2] = bflo(u.y); f[3] = bfhi(u.y);
}

// ---------------- fp32 -> bf16 convert, 3 arrays in one launch ----------------
__global__ __launch_bounds__(256) void cvt3(const float* __restrict__ x, ushort* __restrict__ xb, int nx4,
                                            const float* __restrict__ w1, ushort* __restrict__ w1b, int nw14,
                                            const float* __restrict__ w2, ushort* __restrict__ w2b, int nw24) {
    int i = blockIdx.x * 256 + threadIdx.x;
    const float* src; ushort* dst; int j = i;
    if (j < nx4) { src = x; dst = xb; }
    else {
        j -= nx4;
        if (j < nw14) { src = w1; dst = w1b; }
        else {
            j -= nw14;
            if (j >= nw24) return;
            src = w2; dst = w2b;
        }
    }
    float4 v = ((const float4*)src)[j];
    uint2 o;
    o.x = pack2(v.x, v.y);
    o.y = pack2(v.z, v.w);
    ((uint2*)dst)[j] = o;
}

// ---------------- MFMA GEMM + fused attention-score epilogue ----------------
// C[M,N] = A[M,K]*B[N,K]^T (bf16 in, fp32 acc, bf16 out). 128x128 tile,
// 4 waves, each a 64x64 quadrant of 16x16x32 MFMAs.
// Fused scores: sout[row*H+head] = sum_c h[row,head,c]*att_s[head,c] computed
// from fp32 acc. H==8: each (row,head) owned by one wave -> plain store.
// H==1: two waves share a row -> atomicAdd (sout/dout pre-zeroed).
#define LDSB 40
__global__ __launch_bounds__(256) void gemm_mfma(const ushort* __restrict__ A,
                                                 const ushort* __restrict__ B,
                                                 ushort* __restrict__ C,
                                                 int M, int N, int K,
                                                 const float* __restrict__ att_s,
                                                 const float* __restrict__ att_d,
                                                 float* __restrict__ sout,
                                                 float* __restrict__ dout,
                                                 int H) {
    __shared__ ushort As[128 * LDSB];
    __shared__ ushort Bs[128 * LDSB];
    int t = threadIdx.x;
    int wave = t >> 6, lane = t & 63;
    int quad = lane >> 4, l16 = lane & 15;
    int m0 = blockIdx.x * 128;
    int n0 = blockIdx.y * 128;
    int wm = (wave & 1) * 64;
    int wn = (wave >> 1) * 64;
    int srow = t >> 1;
    int sseg = (t & 1) * 16;          // element offset (16 bf16 = 32 B)
    f32x4 acc[4][4] = {};             // [mi][nj]
    for (int k0 = 0; k0 < K; k0 += 32) {
        uint4 av0, av1, bv0, bv1;
        {
            int grow = m0 + srow;
            if (grow < M) {
                const uint4* gp = (const uint4*)(A + (size_t)grow * K + k0 + sseg);
                av0 = gp[0]; av1 = gp[1];
            } else {
                av0 = make_uint4(0, 0, 0, 0); av1 = av0;
            }
            const uint4* gq = (const uint4*)(B + (size_t)(n0 + srow) * K + k0 + sseg);
            bv0 = gq[0]; bv1 = gq[1];
        }
        __syncthreads();   // previous chunk's LDS readers done
        *(uint4*)&As[srow * LDSB + sseg]     = av0;
        *(uint4*)&As[srow * LDSB + sseg + 8] = av1;
        *(uint4*)&Bs[srow * LDSB + sseg]     = bv0;
        *(uint4*)&Bs[srow * LDSB + sseg + 8] = bv1;
        __syncthreads();
        bf16x8 af[4], bf[4];
#pragma unroll
        for (int i = 0; i < 4; ++i)
            af[i] = *(const bf16x8*)&As[(wm + i * 16 + l16) * LDSB + quad * 8];
#pragma unroll
        for (int j = 0; j < 4; ++j)
            bf[j] = *(const bf16x8*)&Bs[(wn + j * 16 + l16) * LDSB + quad * 8];
#pragma unroll
        for (int i = 0; i < 4; ++i)
#pragma unroll
            for (int j = 0; j < 4; ++j)
                acc[i][j] = __builtin_amdgcn_mfma_f32_16x16x32_bf16(
                    af[i], bf[j], acc[i][j], 0, 0, 0);
    }
    // epilogue: C/D layout col=lane&15, row=quad*4+reg
#pragma unroll
    for (int i = 0; i < 4; ++i) {
#pragma unroll
        for (int r = 0; r < 4; ++r) {
            int grow = m0 + wm + i * 16 + quad * 4 + r;
            if (grow < M) {
#pragma unroll
                for (int j = 0; j < 4; ++j) {
                    int gcol = n0 + wn + j * 16 + l16;
                    C[(size_t)grow * N + gcol] = f2bf(acc[i][j][r]);
                }
            }
        }
    }
    // fused score epilogue
    float as[4], adw[4];
#pragma unroll
    for (int j = 0; j < 4; ++j) {
        int col = n0 + wn + j * 16 + l16;   // flat index into att (H*C = N)
        as[j]  = att_s[col];
        adw[j] = att_d[col];
    }
    int head = (H == 8) ? ((n0 + wn) >> 6) : 0;
#pragma unroll
    for (int i = 0; i < 4; ++i) {
#pragma unroll
        for (int r = 0; r < 4; ++r) {
            float ps = acc[i][0][r] * as[0] + acc[i][1][r] * as[1] +
                       acc[i][2][r] * as[2] + acc[i][3][r] * as[3];
            float pd = acc[i][0][r] * adw[0] + acc[i][1][r] * adw[1] +
                       acc[i][2][r] * adw[2] + acc[i][3][r] * adw[3];
#pragma unroll
            for (int off = 1; off < 16; off <<= 1) {
                ps += __shfl_xor(ps, off);
                pd += __shfl_xor(pd, off);
            }
            int grow = m0 + wm + i * 16 + quad * 4 + r;
            if (l16 == 0 && grow < M) {
                if (H == 1) {
                    atomicAdd(&sout[grow], ps);
                    atomicAdd(&dout[grow], pd);
                } else {
                    sout[grow * 8 + head] = ps;
                    dout[grow * 8 + head] = pd;
                }
            }
        }
    }
}

// ---------------- CSR build ----------------
__global__ void count_edges(const int* __restrict__ dst, int* cnt, int E) {
    int e = blockIdx.x * 256 + threadIdx.x;
    if (e < E) atomicAdd(&cnt[dst[e]], 1);
}

__global__ __launch_bounds__(1024) void scan_offsets(const int* cnt, int* row_start,
                                                     int* cursor, int N) {
    __shared__ int sm[1024];
    int t = threadIdx.x;
    int per = (N + 1023) / 1024;
    int beg = t * per;
    int end = beg + per; if (end > N) end = N;
    int sum = 0;
    for (int i = beg; i < end; ++i) sum += cnt[i];
    sm[t] = sum;
    __syncthreads();
    for (int off = 1; off < 1024; off <<= 1) {
        int add = (t >= off) ? sm[t - off] : 0;
        __syncthreads();
        sm[t] += add;
        __syncthreads();
    }
    int run = sm[t] - sum;
    for (int i = beg; i < end; ++i) {
        int c = cnt[i];
        row_start[i] = run;
        cursor[i] = run;
        run += c;
    }
    if (t == 1023) row_start[N] = run;
}

__global__ void fill_edges(const int* __restrict__ src, const int* __restrict__ dst,
                           int* cursor, int* __restrict__ srcs, int E) {
    int e = blockIdx.x * 256 + threadIdx.x;
    if (e < E) {
        int pos = atomicAdd(&cursor[dst[e]], 1);
        srcs[pos] = src[e];
    }
}

// -------- Layer-1 softmax-aggregate, wave=node, masked 8-deep unroll --------
// 64 lanes = 8 heads x 8 feats, 16B/lane gathers; 8 edges in flight.
__global__ __launch_bounds__(256) void agg1(const ushort* __restrict__ h1,
                                            const float* __restrict__ a1s,
                                            const float* __restrict__ a1d,
                                            const int* __restrict__ row_start,
                                            const int* __restrict__ srcs,
                                            const float* __restrict__ b1,
                                            ushort* __restrict__ r1, int N) {
    int node = blockIdx.x * 4 + (threadIdx.x >> 6);
    if (node >= N) return;
    int lane = threadIdx.x & 63;
    int head = lane >> 3;
    int f0 = lane * 8;
    int pbeg = row_start[node], pend = row_start[node + 1];
    float ad = a1d[node * 8 + head];
    float es = a1s[node * 8 + head] + ad;
    es = es > 0.f ? es : NEG_SLOPE * es;
    float ex_self = __expf(es);
    float den = ex_self;
    float q[8];
    unpack8(*(const uint4*)(h1 + (size_t)node * 512 + f0), q);
    float acc[8];
#pragma unroll
    for (int j = 0; j < 8; ++j) acc[j] = ex_self * q[j];
    for (int p = pbeg; p < pend; p += 8) {
        int sidx[8]; bool okb[8];
#pragma unroll
        for (int k = 0; k < 8; ++k) {
            int pk = p + k;
            okb[k] = pk < pend;
            sidx[k] = srcs[okb[k] ? pk : pbeg];
        }
        uint4 u[8];
#pragma unroll
        for (int k = 0; k < 8; ++k)
            u[k] = *(const uint4*)(h1 + (size_t)sidx[k] * 512 + f0);
        float sc[8];
#pragma unroll
        for (int k = 0; k < 8; ++k) sc[k] = a1s[sidx[k] * 8 + head];
#pragma unroll
        for (int k = 0; k < 8; ++k) {
            float e = sc[k] + ad;
            e = e > 0.f ? e : NEG_SLOPE * e;
            float xk = okb[k] ? __expf(e) : 0.f;
            den += xk;
            float v[8];
            unpack8(u[k], v);
#pragma unroll
            for (int j = 0; j < 8; ++j) acc[j] += xk * v[j];
        }
    }
    float rden = 1.0f / (den + 1e-16f);
    const float4* bp = (const float4*)(b1 + f0);
    float4 b0 = bp[0], b1v = bp[1];
    float o[8];
    o[0] = fmaxf(acc[0] * rden + b0.x, 0.f);
    o[1] = fmaxf(acc[1] * rden + b0.y, 0.f);
    o[2] = fmaxf(acc[2] * rden + b0.z, 0.f);
    o[3] = fmaxf(acc[3] * rden + b0.w, 0.f);
    o[4] = fmaxf(acc[4] * rden + b1v.x, 0.f);
    o[5] = fmaxf(acc[5] * rden + b1v.y, 0.f);
    o[6] = fmaxf(acc[6] * rden + b1v.z, 0.f);
    o[7] = fmaxf(acc[7] * rden + b1v.w, 0.f);
    uint4 ov;
    ov.x = pack2(o[0], o[1]); ov.y = pack2(o[2], o[3]);
    ov.z = pack2(o[4], o[5]); ov.w = pack2(o[6], o[7]);
    *(uint4*)(r1 + (size_t)node * 512 + f0) = ov;
}

// ---------------- Layer-2 single-pass aggregate: 2 nodes per wave, 4-deep unroll ----
__global__ __launch_bounds__(256) void agg2(const ushort* __restrict__ h2,
                                            const float* __restrict__ a2s,
                                            const float* __restrict__ a2d,
                                            const int* __restrict__ row_start,
                                            const int* __restrict__ srcs,
                                            const float* __restrict__ b2,
                                            float* __restrict__ r2, int N) {
    int node = blockIdx.x * 8 + (threadIdx.x >> 5);
    if (node >= N) return;
    int sub = threadIdx.x & 31;
    int f0 = sub * 4;
    int pbeg = row_start[node], pend = row_start[node + 1];
    float ad = a2d[node];
    float es = a2s[node] + ad;
    es = es > 0.f ? es : NEG_SLOPE * es;
    float ex_self = __expf(es);
    float den = ex_self;
    float q[4];
    unpack4(*(const uint2*)(h2 + (size_t)node * 128 + f0), q);
    float acc[4];
#pragma unroll
    for (int j = 0; j < 4; ++j) acc[j] = ex_self * q[j];
    int p = pbeg;
    for (; p + 4 <= pend; p += 4) {
        int s0 = srcs[p + 0];
        int s1 = srcs[p + 1];
        int s2 = srcs[p + 2];
        int s3 = srcs[p + 3];
        uint2 u0 = *(const uint2*)(h2 + (size_t)s0 * 128 + f0);
        uint2 u1 = *(const uint2*)(h2 + (size_t)s1 * 128 + f0);
        uint2 u2 = *(const uint2*)(h2 + (size_t)s2 * 128 + f0);
        uint2 u3 = *(const uint2*)(h2 + (size_t)s3 * 128 + f0);
        float as0 = a2s[s0];
        float as1 = a2s[s1];
        float as2 = a2s[s2];
        float as3 = a2s[s3];
        float e0 = as0 + ad; e0 = e0 > 0.f ? e0 : NEG_SLOPE * e0;
        float e1 = as1 + ad; e1 = e1 > 0.f ? e1 : NEG_SLOPE * e1;
        float e2 = as2 + ad; e2 = e2 > 0.f ? e2 : NEG_SLOPE * e2;
        float e3 = as3 + ad; e3 = e3 > 0.f ? e3 : NEG_SLOPE * e3;
        float x0 = __expf(e0), x1 = __expf(e1), x2 = __expf(e2), x3 = __expf(e3);
        den += (x0 + x1) + (x2 + x3);
        float v[4];
        unpack4(u0, v);
#pragma unroll
        for (int j = 0; j < 4; ++j) acc[j] += x0 * v[j];
        unpack4(u1, v);
#pragma unroll
        for (int j = 0; j < 4; ++j) acc[j] += x1 * v[j];
        unpack4(u2, v);
#pragma unroll
        for (int j = 0; j < 4; ++j) acc[j] += x2 * v[j];
        unpack4(u3, v);
#pragma unroll
        for (int j = 0; j < 4; ++j) acc[j] += x3 * v[j];
    }
    for (; p < pend; ++p) {
        int s = srcs[p];
        float e = a2s[s] + ad;
        e = e > 0.f ? e : NEG_SLOPE * e;
        float ex = __expf(e);
        den += ex;
        float v[4];
        unpack4(*(const uint2*)(h2 + (size_t)s * 128 + f0), v);
#pragma unroll
        for (int j = 0; j < 4; ++j) acc[j] += ex * v[j];
    }
    float rden = 1.0f / (den + 1e-16f);
    float4 bv = *(const float4*)(b2 + f0);
    float4 o;
    o.x = fmaxf(acc[0] * rden + bv.x, 0.f);
    o.y = fmaxf(acc[1] * rden + bv.y, 0.f);
    o.z = fmaxf(acc[2] * rden + bv.z, 0.f);
    o.w = fmaxf(acc[3] * rden + bv.w, 0.f);
    *(float4*)(r2 + (size_t)node * 128 + f0) = o;
}

// ---------------- Attention pooling ----------------
__global__ __launch_bounds__(256) void pool_kernel(const float* __restrict__ r2,
                                                   const int* __restrict__ batch,
                                                   const float* __restrict__ w_attn,
                                                   const float* __restrict__ b_attn,
                                                   const float* __restrict__ w_mask,
                                                   const float* __restrict__ b_mask,
                                                   float* pooled, int N) {
    int node = blockIdx.x * 4 + (threadIdx.x >> 6);
    if (node >= N) return;
    int lane = threadIdx.x & 63;
    float2 h = *(const float2*)(r2 + (size_t)node * 128 + lane * 2);
    float2 wa = *(const float2*)(w_attn + lane * 2);
    float2 wm = *(const float2*)(w_mask + lane * 2);
    float pa = h.x * wa.x + h.y * wa.y;
    float pm = h.x * wm.x + h.y * wm.y;
#pragma unroll
    for (int off = 1; off < 64; off <<= 1) {
        pa += __shfl_xor(pa, off);
        pm += __shfl_xor(pm, off);
    }
    float attn = pa + b_attn[0];
    float mask = 1.0f / (1.0f + __expf(-(pm + b_mask[0])));
    float w = attn * mask;
    int g = batch[node];
    atomicAdd(&pooled[g * 128 + lane * 2], h.x * w);
    atomicAdd(&pooled[g * 128 + lane * 2 + 1], h.y * w);
}

// ---------------- Final tiny GEMM: out[256,2] ----------------
__global__ void final_kernel(const float* __restrict__ pooled,
                             const float* __restrict__ W_out,
                             const float* __restrict__ b_out,
                             float* __restrict__ out) {
    int tid = blockIdx.x * 256 + threadIdx.x;
    if (tid >= 512) return;
    int g = tid >> 1, o = tid & 1;
    const float* p = pooled + g * 128;
    const float* w = W_out + o * 128;
    float s = 0.f;
#pragma unroll 4
    for (int f = 0; f < 128; ++f) s += p[f] * w[f];
    out[tid] = s + b_out[o];
}

extern "C" void kernel_launch(void* const* d_in, const int* in_sizes, int n_in,
                              void* d_out, int out_size, void* d_ws, size_t ws_size,
                              hipStream_t stream) {
    const float* x        = (const float*)d_in[0];
    const int* edge_index = (const int*)d_in[1];
    const int* batch      = (const int*)d_in[2];
    const float* W1       = (const float*)d_in[3];
    const float* att_src1 = (const float*)d_in[4];
    const float* att_dst1 = (const float*)d_in[5];
    const float* b1       = (const float*)d_in[6];
    const float* W2       = (const float*)d_in[7];
    const float* att_src2 = (const float*)d_in[8];
    const float* att_dst2 = (const float*)d_in[9];
    const float* b2       = (const float*)d_in[10];
    const float* w_attn   = (const float*)d_in[11];
    const float* b_attn   = (const float*)d_in[12];
    const float* w_mask   = (const float*)d_in[13];
    const float* b_mask   = (const float*)d_in[14];
    const float* W_out    = (const float*)d_in[15];
    const float* b_out    = (const float*)d_in[16];
    float* out = (float*)d_out;

    int N = in_sizes[0] / 128;
    int E = in_sizes[1] / 2;
    const int* esrc = edge_index;
    const int* edst = edge_index + E;

    char* ws = (char*)d_ws;
    size_t off = 0;
    auto alloc = [&](size_t bytes) {
        void* p = ws + off;
        off = (off + bytes + 255) & ~(size_t)255;
        return p;
    };
    ushort* h1       = (ushort*)alloc((size_t)N * 512 * 2);   // bf16
    ushort* r1       = (ushort*)alloc((size_t)N * 512 * 2);   // bf16
    ushort* h2       = (ushort*)alloc((size_t)N * 128 * 2);   // bf16
    float*  r2       = (float*)alloc((size_t)N * 128 * 4);
    ushort* xb       = (ushort*)alloc((size_t)N * 128 * 2);   // bf16 x
    ushort* w1b      = (ushort*)alloc((size_t)512 * 128 * 2);
    ushort* w2b      = (ushort*)alloc((size_t)128 * 512 * 2);
    float*  a1s      = (float*)alloc((size_t)N * 8 * 4);
    float*  a1d      = (float*)alloc((size_t)N * 8 * 4);
    int*    row_start= (int*)alloc((size_t)(N + 1) * 4);
    int*    srcs     = (int*)alloc((size_t)E * 4);
    // zero-init region: cursor, a2s, a2d, pooled (contiguous, one memset)
    int*    cursor   = (int*)alloc((size_t)N * 4);
    float*  a2s      = (float*)alloc((size_t)N * 4);
    float*  a2d      = (float*)alloc((size_t)N * 4);
    float*  pooled   = (float*)alloc((size_t)256 * 128 * 4);
    size_t zspan = (size_t)((char*)(pooled + 256 * 128) - (char*)cursor);
    hipMemsetAsync(cursor, 0, zspan, stream);

    dim3 b256(256);
    // converts (one launch)
    int nx4 = N * 128 / 4;
    int nw4 = 512 * 128 / 4;
    cvt3<<<(nx4 + 2 * nw4 + 255) / 256, b256, 0, stream>>>(x, xb, nx4, W1, w1b, nw4,
                                                           W2, w2b, nw4);
    // CSR build
    count_edges<<<(E + 255) / 256, b256, 0, stream>>>(edst, cursor, E);
    scan_offsets<<<1, 1024, 0, stream>>>(cursor, row_start, cursor, N);
    fill_edges<<<(E + 255) / 256, b256, 0, stream>>>(esrc, edst, cursor, srcs, E);
    // layer 1 (scores fused into gemm epilogue)
    gemm_mfma<<<dim3((N + 127) / 128, 512 / 128), b256, 0, stream>>>(
        xb, w1b, h1, N, 512, 128, att_src1, att_dst1, a1s, a1d, 8);
    agg1<<<(N + 3) / 4, b256, 0, stream>>>(h1, a1s, a1d, row_start, srcs, b1, r1, N);
    // layer 2 (scores fused, atomic accumulate into zeroed a2s/a2d)
    gemm_mfma<<<dim3((N + 127) / 128, 128 / 128), b256, 0, stream>>>(
        r1, w2b, h2, N, 128, 512, att_src2, att_dst2, a2s, a2d, 1);
    agg2<<<(N + 7) / 8, b256, 0, stream>>>(h2, a2s, a2d, row_start, srcs, b2, r2, N);
    // pooling + head
    pool_kernel<<<(N + 3) / 4, b256, 0, stream>>>(r2, batch, w_attn, b_attn, w_mask,
                                                  b_mask, pooled, N);
    final_kernel<<<2, b256, 0, stream>>>(pooled, W_out, b_out, out);
}

// Round 7
// 291.077 us; speedup vs baseline: 1.1426x; 1.0105x over previous
//
#include <hip/hip_runtime.h>
#include <math.h>

// R4: agg1 4-deep unroll = 49.2us (best). R7: scores fused into gemm epilogues
// (passed, 294us); agg1 8-deep regressed (51us, occ 38%). Launch gaps measured
// small (~2-4us) => ~190us hides in the 10 sub-51us dispatches.
// R9: (1) agg1 reverted to R4 4-deep body; (2) GEMM staging software-pipelined
// (preload next K-chunk to regs before MFMA => overlap HBM latency, helps the
// 157-block latency-serial gemm2 most); (3) block-range fusions: cvt+count ->
// prep, gemm1+fill -> one launch, agg2+pool -> one kernel dropping r2 buffer
// entirely (20MB traffic). 12 -> 8 dispatches.

#define NEG_SLOPE 0.2f
#define LDSB 40

using bf16x8 = __attribute__((ext_vector_type(8))) __bf16;
using f32x4  = __attribute__((ext_vector_type(4))) float;

// ---------- bf16 helpers (storage ushort, fp32 compute) ----------
__device__ __forceinline__ ushort f2bf(float f) {
    unsigned u = __float_as_uint(f);
    unsigned r = (u + 0x7FFFu + ((u >> 16) & 1u)) >> 16;   // RNE
    return (ushort)r;
}
__device__ __forceinline__ unsigned pack2(float a, float b) {
    return (unsigned)f2bf(a) | ((unsigned)f2bf(b) << 16);
}
__device__ __forceinline__ float bflo(unsigned u) { return __uint_as_float(u << 16); }
__device__ __forceinline__ float bfhi(unsigned u) { return __uint_as_float(u & 0xFFFF0000u); }
__device__ __forceinline__ void unpack8(uint4 u, float* f) {
    f[0] = bflo(u.x); f[1] = bfhi(u.x);
    f[2] = bflo(u.y); f[3] = bfhi(u.y);
    f[4] = bflo(u.z); f[5] = bfhi(u.z);
    f[6] = bflo(u.w); f[7] = bfhi(u.w);
}
__device__ __forceinline__ void unpack4(uint2 u, float* f) {
    f[0] = bflo(u.x); f[1] = bfhi(u.x);
    f[2] = bflo(u.y); f[3] = bfhi(u.y);
}

// ---------------- prep: bf16 converts (blocks [0,cvtBlocks)) + edge count ----
__global__ __launch_bounds__(256) void prep(const float* __restrict__ x, ushort* __restrict__ xb, int nx4,
                                            const float* __restrict__ w1, ushort* __restrict__ w1b, int nw14,
                                            const float* __restrict__ w2, ushort* __restrict__ w2b, int nw24,
                                            int cvtBlocks,
                                            const int* __restrict__ edst, int* __restrict__ cnt, int E) {
    int blk = blockIdx.x;
    if (blk < cvtBlocks) {
        int j = blk * 256 + threadIdx.x;
        const float* src; ushort* dst;
        if (j < nx4) { src = x; dst = xb; }
        else {
            j -= nx4;
            if (j < nw14) { src = w1; dst = w1b; }
            else {
                j -= nw14;
                if (j >= nw24) return;
                src = w2; dst = w2b;
            }
        }
        float4 v = ((const float4*)src)[j];
        uint2 o;
        o.x = pack2(v.x, v.y);
        o.y = pack2(v.z, v.w);
        ((uint2*)dst)[j] = o;
    } else {
        int e = (blk - cvtBlocks) * 256 + threadIdx.x;
        if (e < E) atomicAdd(&cnt[edst[e]], 1);
    }
}

// ---------------- GEMM body: C[M,N]=A[M,K]*B[N,K]^T, software-pipelined ------
// 128x128 tile, 4 waves, 16x16x32 MFMAs; next K-chunk preloaded to regs before
// the MFMA block so HBM latency overlaps compute. Fused score epilogue
// (sout/dout) as R7: H==8 plain store, H==1 atomicAdd into zeroed buffers.
__device__ __forceinline__ void gemm_body(ushort* As, ushort* Bs,
                                          const ushort* __restrict__ A,
                                          const ushort* __restrict__ B,
                                          ushort* __restrict__ C,
                                          int M, int N, int K, int bx, int by,
                                          const float* __restrict__ att_s,
                                          const float* __restrict__ att_d,
                                          float* __restrict__ sout,
                                          float* __restrict__ dout, int H) {
    int t = threadIdx.x;
    int wave = t >> 6, lane = t & 63;
    int quad = lane >> 4, l16 = lane & 15;
    int m0 = bx * 128, n0 = by * 128;
    int wm = (wave & 1) * 64;
    int wn = (wave >> 1) * 64;
    int srow = t >> 1;
    int sseg = (t & 1) * 16;          // element offset (16 bf16 = 32 B)
    int growA = m0 + srow;
    bool okA = growA < M;
    f32x4 acc[4][4] = {};             // [mi][nj]
    uint4 av0, av1, bv0, bv1;
    {   // preload chunk 0
        if (okA) {
            const uint4* gp = (const uint4*)(A + (size_t)growA * K + sseg);
            av0 = gp[0]; av1 = gp[1];
        } else { av0 = make_uint4(0, 0, 0, 0); av1 = av0; }
        const uint4* gq = (const uint4*)(B + (size_t)(n0 + srow) * K + sseg);
        bv0 = gq[0]; bv1 = gq[1];
    }
    for (int k0 = 0; k0 < K; k0 += 32) {
        __syncthreads();   // previous chunk's LDS readers done
        *(uint4*)&As[srow * LDSB + sseg]     = av0;
        *(uint4*)&As[srow * LDSB + sseg + 8] = av1;
        *(uint4*)&Bs[srow * LDSB + sseg]     = bv0;
        *(uint4*)&Bs[srow * LDSB + sseg + 8] = bv1;
        __syncthreads();
        int k1 = k0 + 32;
        if (k1 < K) {   // issue next-chunk loads BEFORE compute (overlap)
            if (okA) {
                const uint4* gp = (const uint4*)(A + (size_t)growA * K + k1 + sseg);
                av0 = gp[0]; av1 = gp[1];
            } else { av0 = make_uint4(0, 0, 0, 0); av1 = av0; }
            const uint4* gq = (const uint4*)(B + (size_t)(n0 + srow) * K + k1 + sseg);
            bv0 = gq[0]; bv1 = gq[1];
        }
        bf16x8 af[4], bf[4];
#pragma unroll
        for (int i = 0; i < 4; ++i)
            af[i] = *(const bf16x8*)&As[(wm + i * 16 + l16) * LDSB + quad * 8];
#pragma unroll
        for (int j = 0; j < 4; ++j)
            bf[j] = *(const bf16x8*)&Bs[(wn + j * 16 + l16) * LDSB + quad * 8];
#pragma unroll
        for (int i = 0; i < 4; ++i)
#pragma unroll
            for (int j = 0; j < 4; ++j)
                acc[i][j] = __builtin_amdgcn_mfma_f32_16x16x32_bf16(
                    af[i], bf[j], acc[i][j], 0, 0, 0);
    }
    // epilogue: C/D layout col=lane&15, row=quad*4+reg
#pragma unroll
    for (int i = 0; i < 4; ++i) {
#pragma unroll
        for (int r = 0; r < 4; ++r) {
            int grow = m0 + wm + i * 16 + quad * 4 + r;
            if (grow < M) {
#pragma unroll
                for (int j = 0; j < 4; ++j) {
                    int gcol = n0 + wn + j * 16 + l16;
                    C[(size_t)grow * N + gcol] = f2bf(acc[i][j][r]);
                }
            }
        }
    }
    // fused score epilogue
    float as[4], adw[4];
#pragma unroll
    for (int j = 0; j < 4; ++j) {
        int col = n0 + wn + j * 16 + l16;   // flat index into att (H*C = N)
        as[j]  = att_s[col];
        adw[j] = att_d[col];
    }
    int head = (H == 8) ? ((n0 + wn) >> 6) : 0;
#pragma unroll
    for (int i = 0; i < 4; ++i) {
#pragma unroll
        for (int r = 0; r < 4; ++r) {
            float ps = acc[i][0][r] * as[0] + acc[i][1][r] * as[1] +
                       acc[i][2][r] * as[2] + acc[i][3][r] * as[3];
            float pd = acc[i][0][r] * adw[0] + acc[i][1][r] * adw[1] +
                       acc[i][2][r] * adw[2] + acc[i][3][r] * adw[3];
#pragma unroll
            for (int off = 1; off < 16; off <<= 1) {
                ps += __shfl_xor(ps, off);
                pd += __shfl_xor(pd, off);
            }
            int grow = m0 + wm + i * 16 + quad * 4 + r;
            if (l16 == 0 && grow < M) {
                if (H == 1) {
                    atomicAdd(&sout[grow], ps);
                    atomicAdd(&dout[grow], pd);
                } else {
                    sout[grow * 8 + head] = ps;
                    dout[grow * 8 + head] = pd;
                }
            }
        }
    }
}

// ---------------- fused gemm1 + fill_edges (independent work, block-split) ----
__global__ __launch_bounds__(256) void g1f(const ushort* __restrict__ A,
                                           const ushort* __restrict__ B,
                                           ushort* __restrict__ C,
                                           int M, int N, int K,
                                           const float* __restrict__ att_s,
                                           const float* __restrict__ att_d,
                                           float* __restrict__ sout,
                                           float* __restrict__ dout, int H,
                                           int gemmBlocks, int nby,
                                           const int* __restrict__ esrc,
                                           const int* __restrict__ edst,
                                           int* __restrict__ cursor,
                                           int* __restrict__ srcs, int E) {
    __shared__ ushort As[128 * LDSB];
    __shared__ ushort Bs[128 * LDSB];
    int blk = blockIdx.x;
    if (blk < gemmBlocks) {
        gemm_body(As, Bs, A, B, C, M, N, K, blk / nby, blk % nby,
                  att_s, att_d, sout, dout, H);
    } else {
        int e = (blk - gemmBlocks) * 256 + threadIdx.x;
        if (e < E) {
            int pos = atomicAdd(&cursor[edst[e]], 1);
            srcs[pos] = esrc[e];
        }
    }
}

// ---------------- plain GEMM kernel (layer 2) ----------------
__global__ __launch_bounds__(256) void gemm_k(const ushort* __restrict__ A,
                                              const ushort* __restrict__ B,
                                              ushort* __restrict__ C,
                                              int M, int N, int K,
                                              const float* __restrict__ att_s,
                                              const float* __restrict__ att_d,
                                              float* __restrict__ sout,
                                              float* __restrict__ dout, int H,
                                              int nby) {
    __shared__ ushort As[128 * LDSB];
    __shared__ ushort Bs[128 * LDSB];
    gemm_body(As, Bs, A, B, C, M, N, K, blockIdx.x / nby, blockIdx.x % nby,
              att_s, att_d, sout, dout, H);
}

// ---------------- CSR scan ----------------
__global__ __launch_bounds__(1024) void scan_offsets(const int* cnt, int* row_start,
                                                     int* cursor, int N) {
    __shared__ int sm[1024];
    int t = threadIdx.x;
    int per = (N + 1023) / 1024;
    int beg = t * per;
    int end = beg + per; if (end > N) end = N;
    int sum = 0;
    for (int i = beg; i < end; ++i) sum += cnt[i];
    sm[t] = sum;
    __syncthreads();
    for (int off = 1; off < 1024; off <<= 1) {
        int add = (t >= off) ? sm[t - off] : 0;
        __syncthreads();
        sm[t] += add;
        __syncthreads();
    }
    int run = sm[t] - sum;
    for (int i = beg; i < end; ++i) {
        int c = cnt[i];
        row_start[i] = run;
        cursor[i] = run;
        run += c;
    }
    if (t == 1023) row_start[N] = run;
}

// -------- Layer-1 softmax-aggregate (R4 structure: 4-deep unroll + tail) -----
__global__ __launch_bounds__(256) void agg1(const ushort* __restrict__ h1,
                                            const float* __restrict__ a1s,
                                            const float* __restrict__ a1d,
                                            const int* __restrict__ row_start,
                                            const int* __restrict__ srcs,
                                            const float* __restrict__ b1,
                                            ushort* __restrict__ r1, int N) {
    int node = blockIdx.x * 4 + (threadIdx.x >> 6);
    if (node >= N) return;
    int lane = threadIdx.x & 63;
    int head = lane >> 3;
    int f0 = lane * 8;
    int pbeg = row_start[node], pend = row_start[node + 1];
    float ad = a1d[node * 8 + head];
    float es = a1s[node * 8 + head] + ad;
    es = es > 0.f ? es : NEG_SLOPE * es;
    float ex_self = __expf(es);
    float den = ex_self;
    float q[8];
    unpack8(*(const uint4*)(h1 + (size_t)node * 512 + f0), q);
    float acc[8];
#pragma unroll
    for (int j = 0; j < 8; ++j) acc[j] = ex_self * q[j];
    int p = pbeg;
    for (; p + 4 <= pend; p += 4) {
        int s0 = srcs[p + 0];
        int s1 = srcs[p + 1];
        int s2 = srcs[p + 2];
        int s3 = srcs[p + 3];
        uint4 u0 = *(const uint4*)(h1 + (size_t)s0 * 512 + f0);
        uint4 u1 = *(const uint4*)(h1 + (size_t)s1 * 512 + f0);
        uint4 u2 = *(const uint4*)(h1 + (size_t)s2 * 512 + f0);
        uint4 u3 = *(const uint4*)(h1 + (size_t)s3 * 512 + f0);
        float as0 = a1s[s0 * 8 + head];
        float as1 = a1s[s1 * 8 + head];
        float as2 = a1s[s2 * 8 + head];
        float as3 = a1s[s3 * 8 + head];
        float e0 = as0 + ad; e0 = e0 > 0.f ? e0 : NEG_SLOPE * e0;
        float e1 = as1 + ad; e1 = e1 > 0.f ? e1 : NEG_SLOPE * e1;
        float e2 = as2 + ad; e2 = e2 > 0.f ? e2 : NEG_SLOPE * e2;
        float e3 = as3 + ad; e3 = e3 > 0.f ? e3 : NEG_SLOPE * e3;
        float x0 = __expf(e0), x1 = __expf(e1), x2 = __expf(e2), x3 = __expf(e3);
        den += (x0 + x1) + (x2 + x3);
        float v[8];
        unpack8(u0, v);
#pragma unroll
        for (int j = 0; j < 8; ++j) acc[j] += x0 * v[j];
        unpack8(u1, v);
#pragma unroll
        for (int j = 0; j < 8; ++j) acc[j] += x1 * v[j];
        unpack8(u2, v);
#pragma unroll
        for (int j = 0; j < 8; ++j) acc[j] += x2 * v[j];
        unpack8(u3, v);
#pragma unroll
        for (int j = 0; j < 8; ++j) acc[j] += x3 * v[j];
    }
    for (; p < pend; ++p) {
        int s = srcs[p];
        float e = a1s[s * 8 + head] + ad;
        e = e > 0.f ? e : NEG_SLOPE * e;
        float ex = __expf(e);
        den += ex;
        float v[8];
        unpack8(*(const uint4*)(h1 + (size_t)s * 512 + f0), v);
#pragma unroll
        for (int j = 0; j < 8; ++j) acc[j] += ex * v[j];
    }
    float rden = 1.0f / (den + 1e-16f);
    const float4* bp = (const float4*)(b1 + f0);
    float4 b0 = bp[0], b1v = bp[1];
    float o[8];
    o[0] = fmaxf(acc[0] * rden + b0.x, 0.f);
    o[1] = fmaxf(acc[1] * rden + b0.y, 0.f);
    o[2] = fmaxf(acc[2] * rden + b0.z, 0.f);
    o[3] = fmaxf(acc[3] * rden + b0.w, 0.f);
    o[4] = fmaxf(acc[4] * rden + b1v.x, 0.f);
    o[5] = fmaxf(acc[5] * rden + b1v.y, 0.f);
    o[6] = fmaxf(acc[6] * rden + b1v.z, 0.f);
    o[7] = fmaxf(acc[7] * rden + b1v.w, 0.f);
    uint4 ov;
    ov.x = pack2(o[0], o[1]); ov.y = pack2(o[2], o[3]);
    ov.z = pack2(o[4], o[5]); ov.w = pack2(o[6], o[7]);
    *(uint4*)(r1 + (size_t)node * 512 + f0) = ov;
}

// -------- Layer-2 aggregate + attention pooling fused (r2 never materialized) --
// 2 nodes/wave (32 lanes each, 4 feats/lane). After computing the r2 row in
// regs, do the pooling dots + 32-lane reduce + atomicAdd into pooled.
__global__ __launch_bounds__(256) void agg2pool(const ushort* __restrict__ h2,
                                                const float* __restrict__ a2s,
                                                const float* __restrict__ a2d,
                                                const int* __restrict__ row_start,
                                                const int* __restrict__ srcs,
                                                const float* __restrict__ b2,
                                                const int* __restrict__ batch,
                                                const float* __restrict__ w_attn,
                                                const float* __restrict__ b_attn,
                                                const float* __restrict__ w_mask,
                                                const float* __restrict__ b_mask,
                                                float* __restrict__ pooled, int N) {
    int node = blockIdx.x * 8 + (threadIdx.x >> 5);
    if (node >= N) return;
    int sub = threadIdx.x & 31;
    int f0 = sub * 4;
    int pbeg = row_start[node], pend = row_start[node + 1];
    float ad = a2d[node];
    float es = a2s[node] + ad;
    es = es > 0.f ? es : NEG_SLOPE * es;
    float ex_self = __expf(es);
    float den = ex_self;
    float q[4];
    unpack4(*(const uint2*)(h2 + (size_t)node * 128 + f0), q);
    float acc[4];
#pragma unroll
    for (int j = 0; j < 4; ++j) acc[j] = ex_self * q[j];
    int p = pbeg;
    for (; p + 4 <= pend; p += 4) {
        int s0 = srcs[p + 0];
        int s1 = srcs[p + 1];
        int s2 = srcs[p + 2];
        int s3 = srcs[p + 3];
        uint2 u0 = *(const uint2*)(h2 + (size_t)s0 * 128 + f0);
        uint2 u1 = *(const uint2*)(h2 + (size_t)s1 * 128 + f0);
        uint2 u2 = *(const uint2*)(h2 + (size_t)s2 * 128 + f0);
        uint2 u3 = *(const uint2*)(h2 + (size_t)s3 * 128 + f0);
        float as0 = a2s[s0];
        float as1 = a2s[s1];
        float as2 = a2s[s2];
        float as3 = a2s[s3];
        float e0 = as0 + ad; e0 = e0 > 0.f ? e0 : NEG_SLOPE * e0;
        float e1 = as1 + ad; e1 = e1 > 0.f ? e1 : NEG_SLOPE * e1;
        float e2 = as2 + ad; e2 = e2 > 0.f ? e2 : NEG_SLOPE * e2;
        float e3 = as3 + ad; e3 = e3 > 0.f ? e3 : NEG_SLOPE * e3;
        float x0 = __expf(e0), x1 = __expf(e1), x2 = __expf(e2), x3 = __expf(e3);
        den += (x0 + x1) + (x2 + x3);
        float v[4];
        unpack4(u0, v);
#pragma unroll
        for (int j = 0; j < 4; ++j) acc[j] += x0 * v[j];
        unpack4(u1, v);
#pragma unroll
        for (int j = 0; j < 4; ++j) acc[j] += x1 * v[j];
        unpack4(u2, v);
#pragma unroll
        for (int j = 0; j < 4; ++j) acc[j] += x2 * v[j];
        unpack4(u3, v);
#pragma unroll
        for (int j = 0; j < 4; ++j) acc[j] += x3 * v[j];
    }
    for (; p < pend; ++p) {
        int s = srcs[p];
        float e = a2s[s] + ad;
        e = e > 0.f ? e : NEG_SLOPE * e;
        float ex = __expf(e);
        den += ex;
        float v[4];
        unpack4(*(const uint2*)(h2 + (size_t)s * 128 + f0), v);
#pragma unroll
        for (int j = 0; j < 4; ++j) acc[j] += ex * v[j];
    }
    float rden = 1.0f / (den + 1e-16f);
    float4 bv = *(const float4*)(b2 + f0);
    float4 o;
    o.x = fmaxf(acc[0] * rden + bv.x, 0.f);
    o.y = fmaxf(acc[1] * rden + bv.y, 0.f);
    o.z = fmaxf(acc[2] * rden + bv.z, 0.f);
    o.w = fmaxf(acc[3] * rden + bv.w, 0.f);
    // ---- fused pooling ----
    float4 wa = *(const float4*)(w_attn + f0);
    float4 wm = *(const float4*)(w_mask + f0);
    float pa = o.x * wa.x + o.y * wa.y + o.z * wa.z + o.w * wa.w;
    float pm = o.x * wm.x + o.y * wm.y + o.z * wm.z + o.w * wm.w;
#pragma unroll
    for (int off = 1; off < 32; off <<= 1) {
        pa += __shfl_xor(pa, off);
        pm += __shfl_xor(pm, off);
    }
    float attn = pa + b_attn[0];
    float mask = 1.0f / (1.0f + __expf(-(pm + b_mask[0])));
    float w = attn * mask;
    int g = batch[node];
    float* pg = pooled + (size_t)g * 128 + f0;
    atomicAdd(pg + 0, o.x * w);
    atomicAdd(pg + 1, o.y * w);
    atomicAdd(pg + 2, o.z * w);
    atomicAdd(pg + 3, o.w * w);
}

// ---------------- Final tiny GEMM: out[256,2] ----------------
__global__ void final_kernel(const float* __restrict__ pooled,
                             const float* __restrict__ W_out,
                             const float* __restrict__ b_out,
                             float* __restrict__ out) {
    int tid = blockIdx.x * 256 + threadIdx.x;
    if (tid >= 512) return;
    int g = tid >> 1, o = tid & 1;
    const float* p = pooled + g * 128;
    const float* w = W_out + o * 128;
    float s = 0.f;
#pragma unroll 4
    for (int f = 0; f < 128; ++f) s += p[f] * w[f];
    out[tid] = s + b_out[o];
}

extern "C" void kernel_launch(void* const* d_in, const int* in_sizes, int n_in,
                              void* d_out, int out_size, void* d_ws, size_t ws_size,
                              hipStream_t stream) {
    const float* x        = (const float*)d_in[0];
    const int* edge_index = (const int*)d_in[1];
    const int* batch      = (const int*)d_in[2];
    const float* W1       = (const float*)d_in[3];
    const float* att_src1 = (const float*)d_in[4];
    const float* att_dst1 = (const float*)d_in[5];
    const float* b1       = (const float*)d_in[6];
    const float* W2       = (const float*)d_in[7];
    const float* att_src2 = (const float*)d_in[8];
    const float* att_dst2 = (const float*)d_in[9];
    const float* b2       = (const float*)d_in[10];
    const float* w_attn   = (const float*)d_in[11];
    const float* b_attn   = (const float*)d_in[12];
    const float* w_mask   = (const float*)d_in[13];
    const float* b_mask   = (const float*)d_in[14];
    const float* W_out    = (const float*)d_in[15];
    const float* b_out    = (const float*)d_in[16];
    float* out = (float*)d_out;

    int N = in_sizes[0] / 128;
    int E = in_sizes[1] / 2;
    const int* esrc = edge_index;
    const int* edst = edge_index + E;

    char* ws = (char*)d_ws;
    size_t off = 0;
    auto alloc = [&](size_t bytes) {
        void* p = ws + off;
        off = (off + bytes + 255) & ~(size_t)255;
        return p;
    };
    ushort* h1       = (ushort*)alloc((size_t)N * 512 * 2);   // bf16
    ushort* r1       = (ushort*)alloc((size_t)N * 512 * 2);   // bf16
    ushort* h2       = (ushort*)alloc((size_t)N * 128 * 2);   // bf16
    ushort* xb       = (ushort*)alloc((size_t)N * 128 * 2);   // bf16 x
    ushort* w1b      = (ushort*)alloc((size_t)512 * 128 * 2);
    ushort* w2b      = (ushort*)alloc((size_t)128 * 512 * 2);
    float*  a1s      = (float*)alloc((size_t)N * 8 * 4);
    float*  a1d      = (float*)alloc((size_t)N * 8 * 4);
    int*    row_start= (int*)alloc((size_t)(N + 1) * 4);
    int*    srcs     = (int*)alloc((size_t)E * 4);
    // zero-init region: cursor, a2s, a2d, pooled (contiguous, one memset)
    int*    cursor   = (int*)alloc((size_t)N * 4);
    float*  a2s      = (float*)alloc((size_t)N * 4);
    float*  a2d      = (float*)alloc((size_t)N * 4);
    float*  pooled   = (float*)alloc((size_t)256 * 128 * 4);
    size_t zspan = (size_t)((char*)(pooled + 256 * 128) - (char*)cursor);
    hipMemsetAsync(cursor, 0, zspan, stream);

    dim3 b256(256);
    // prep: converts + edge count in one launch
    int nx4 = N * 128 / 4;
    int nw4 = 512 * 128 / 4;
    int cvtBlocks = (nx4 + 2 * nw4 + 255) / 256;
    int cntBlocks = (E + 255) / 256;
    prep<<<cvtBlocks + cntBlocks, b256, 0, stream>>>(x, xb, nx4, W1, w1b, nw4,
                                                     W2, w2b, nw4, cvtBlocks,
                                                     edst, cursor, E);
    scan_offsets<<<1, 1024, 0, stream>>>(cursor, row_start, cursor, N);
    // gemm1 (157x4 tiles, fused scores H=8) + fill_edges in one launch
    int g1Blocks = ((N + 127) / 128) * 4;
    g1f<<<g1Blocks + cntBlocks, b256, 0, stream>>>(xb, w1b, h1, N, 512, 128,
                                                   att_src1, att_dst1, a1s, a1d, 8,
                                                   g1Blocks, 4,
                                                   esrc, edst, cursor, srcs, E);
    agg1<<<(N + 3) / 4, b256, 0, stream>>>(h1, a1s, a1d, row_start, srcs, b1, r1, N);
    // layer 2 gemm (fused scores H=1, atomics into zeroed a2s/a2d)
    gemm_k<<<(N + 127) / 128, b256, 0, stream>>>(r1, w2b, h2, N, 128, 512,
                                                 att_src2, att_dst2, a2s, a2d, 1, 1);
    // layer 2 aggregate + pooling fused (r2 eliminated)
    agg2pool<<<(N + 7) / 8, b256, 0, stream>>>(h2, a2s, a2d, row_start, srcs, b2,
                                               batch, w_attn, b_attn, w_mask, b_mask,
                                               pooled, N);
    final_kernel<<<2, b256, 0, stream>>>(pooled, W_out, b_out, out);
}

// Round 8
// 290.917 us; speedup vs baseline: 1.1432x; 1.0005x over previous
//
#include <hip/hip_runtime.h>
#include <math.h>

// R9 (291us): agg2pool revealed at 55us — VALU 15%, HBM 14%, occ 44% =
// latency-bound + 2.56M pooled atomics (WRITE 40MB). agg1 49us at 6.65 TB/s
// effective gather delivery (mixed L2/L3) — near service plateau, left alone.
// R10: agg2pool gets (a) masked 8-deep edge unroll (32->64 lines in flight),
// (b) pooled+final eliminated: out[g][o] += w_n*(r2_n . W_out[o]) directly
// (40k atomics, not 2.56M); out prefilled with b_out in scan_offsets.
// 8 -> 7 dispatches.

#define NEG_SLOPE 0.2f
#define LDSB 40

using bf16x8 = __attribute__((ext_vector_type(8))) __bf16;
using f32x4  = __attribute__((ext_vector_type(4))) float;

// ---------- bf16 helpers (storage ushort, fp32 compute) ----------
__device__ __forceinline__ ushort f2bf(float f) {
    unsigned u = __float_as_uint(f);
    unsigned r = (u + 0x7FFFu + ((u >> 16) & 1u)) >> 16;   // RNE
    return (ushort)r;
}
__device__ __forceinline__ unsigned pack2(float a, float b) {
    return (unsigned)f2bf(a) | ((unsigned)f2bf(b) << 16);
}
__device__ __forceinline__ float bflo(unsigned u) { return __uint_as_float(u << 16); }
__device__ __forceinline__ float bfhi(unsigned u) { return __uint_as_float(u & 0xFFFF0000u); }
__device__ __forceinline__ void unpack8(uint4 u, float* f) {
    f[0] = bflo(u.x); f[1] = bfhi(u.x);
    f[2] = bflo(u.y); f[3] = bfhi(u.y);
    f[4] = bflo(u.z); f[5] = bfhi(u.z);
    f[6] = bflo(u.w); f[7] = bfhi(u.w);
}
__device__ __forceinline__ void unpack4(uint2 u, float* f) {
    f[0] = bflo(u.x); f[1] = bfhi(u.x);
    f[2] = bflo(u.y); f[3] = bfhi(u.y);
}

// ---------------- prep: bf16 converts (blocks [0,cvtBlocks)) + edge count ----
__global__ __launch_bounds__(256) void prep(const float* __restrict__ x, ushort* __restrict__ xb, int nx4,
                                            const float* __restrict__ w1, ushort* __restrict__ w1b, int nw14,
                                            const float* __restrict__ w2, ushort* __restrict__ w2b, int nw24,
                                            int cvtBlocks,
                                            const int* __restrict__ edst, int* __restrict__ cnt, int E) {
    int blk = blockIdx.x;
    if (blk < cvtBlocks) {
        int j = blk * 256 + threadIdx.x;
        const float* src; ushort* dst;
        if (j < nx4) { src = x; dst = xb; }
        else {
            j -= nx4;
            if (j < nw14) { src = w1; dst = w1b; }
            else {
                j -= nw14;
                if (j >= nw24) return;
                src = w2; dst = w2b;
            }
        }
        float4 v = ((const float4*)src)[j];
        uint2 o;
        o.x = pack2(v.x, v.y);
        o.y = pack2(v.z, v.w);
        ((uint2*)dst)[j] = o;
    } else {
        int e = (blk - cvtBlocks) * 256 + threadIdx.x;
        if (e < E) atomicAdd(&cnt[edst[e]], 1);
    }
}

// ---------------- GEMM body: C[M,N]=A[M,K]*B[N,K]^T, software-pipelined ------
__device__ __forceinline__ void gemm_body(ushort* As, ushort* Bs,
                                          const ushort* __restrict__ A,
                                          const ushort* __restrict__ B,
                                          ushort* __restrict__ C,
                                          int M, int N, int K, int bx, int by,
                                          const float* __restrict__ att_s,
                                          const float* __restrict__ att_d,
                                          float* __restrict__ sout,
                                          float* __restrict__ dout, int H) {
    int t = threadIdx.x;
    int wave = t >> 6, lane = t & 63;
    int quad = lane >> 4, l16 = lane & 15;
    int m0 = bx * 128, n0 = by * 128;
    int wm = (wave & 1) * 64;
    int wn = (wave >> 1) * 64;
    int srow = t >> 1;
    int sseg = (t & 1) * 16;          // element offset (16 bf16 = 32 B)
    int growA = m0 + srow;
    bool okA = growA < M;
    f32x4 acc[4][4] = {};             // [mi][nj]
    uint4 av0, av1, bv0, bv1;
    {   // preload chunk 0
        if (okA) {
            const uint4* gp = (const uint4*)(A + (size_t)growA * K + sseg);
            av0 = gp[0]; av1 = gp[1];
        } else { av0 = make_uint4(0, 0, 0, 0); av1 = av0; }
        const uint4* gq = (const uint4*)(B + (size_t)(n0 + srow) * K + sseg);
        bv0 = gq[0]; bv1 = gq[1];
    }
    for (int k0 = 0; k0 < K; k0 += 32) {
        __syncthreads();   // previous chunk's LDS readers done
        *(uint4*)&As[srow * LDSB + sseg]     = av0;
        *(uint4*)&As[srow * LDSB + sseg + 8] = av1;
        *(uint4*)&Bs[srow * LDSB + sseg]     = bv0;
        *(uint4*)&Bs[srow * LDSB + sseg + 8] = bv1;
        __syncthreads();
        int k1 = k0 + 32;
        if (k1 < K) {   // issue next-chunk loads BEFORE compute (overlap)
            if (okA) {
                const uint4* gp = (const uint4*)(A + (size_t)growA * K + k1 + sseg);
                av0 = gp[0]; av1 = gp[1];
            } else { av0 = make_uint4(0, 0, 0, 0); av1 = av0; }
            const uint4* gq = (const uint4*)(B + (size_t)(n0 + srow) * K + k1 + sseg);
            bv0 = gq[0]; bv1 = gq[1];
        }
        bf16x8 af[4], bf[4];
#pragma unroll
        for (int i = 0; i < 4; ++i)
            af[i] = *(const bf16x8*)&As[(wm + i * 16 + l16) * LDSB + quad * 8];
#pragma unroll
        for (int j = 0; j < 4; ++j)
            bf[j] = *(const bf16x8*)&Bs[(wn + j * 16 + l16) * LDSB + quad * 8];
#pragma unroll
        for (int i = 0; i < 4; ++i)
#pragma unroll
            for (int j = 0; j < 4; ++j)
                acc[i][j] = __builtin_amdgcn_mfma_f32_16x16x32_bf16(
                    af[i], bf[j], acc[i][j], 0, 0, 0);
    }
    // epilogue: C/D layout col=lane&15, row=quad*4+reg
#pragma unroll
    for (int i = 0; i < 4; ++i) {
#pragma unroll
        for (int r = 0; r < 4; ++r) {
            int grow = m0 + wm + i * 16 + quad * 4 + r;
            if (grow < M) {
#pragma unroll
                for (int j = 0; j < 4; ++j) {
                    int gcol = n0 + wn + j * 16 + l16;
                    C[(size_t)grow * N + gcol] = f2bf(acc[i][j][r]);
                }
            }
        }
    }
    // fused score epilogue
    float as[4], adw[4];
#pragma unroll
    for (int j = 0; j < 4; ++j) {
        int col = n0 + wn + j * 16 + l16;   // flat index into att (H*C = N)
        as[j]  = att_s[col];
        adw[j] = att_d[col];
    }
    int head = (H == 8) ? ((n0 + wn) >> 6) : 0;
#pragma unroll
    for (int i = 0; i < 4; ++i) {
#pragma unroll
        for (int r = 0; r < 4; ++r) {
            float ps = acc[i][0][r] * as[0] + acc[i][1][r] * as[1] +
                       acc[i][2][r] * as[2] + acc[i][3][r] * as[3];
            float pd = acc[i][0][r] * adw[0] + acc[i][1][r] * adw[1] +
                       acc[i][2][r] * adw[2] + acc[i][3][r] * adw[3];
#pragma unroll
            for (int off = 1; off < 16; off <<= 1) {
                ps += __shfl_xor(ps, off);
                pd += __shfl_xor(pd, off);
            }
            int grow = m0 + wm + i * 16 + quad * 4 + r;
            if (l16 == 0 && grow < M) {
                if (H == 1) {
                    atomicAdd(&sout[grow], ps);
                    atomicAdd(&dout[grow], pd);
                } else {
                    sout[grow * 8 + head] = ps;
                    dout[grow * 8 + head] = pd;
                }
            }
        }
    }
}

// ---------------- fused gemm1 + fill_edges (independent work, block-split) ----
__global__ __launch_bounds__(256) void g1f(const ushort* __restrict__ A,
                                           const ushort* __restrict__ B,
                                           ushort* __restrict__ C,
                                           int M, int N, int K,
                                           const float* __restrict__ att_s,
                                           const float* __restrict__ att_d,
                                           float* __restrict__ sout,
                                           float* __restrict__ dout, int H,
                                           int gemmBlocks, int nby,
                                           const int* __restrict__ esrc,
                                           const int* __restrict__ edst,
                                           int* __restrict__ cursor,
                                           int* __restrict__ srcs, int E) {
    __shared__ ushort As[128 * LDSB];
    __shared__ ushort Bs[128 * LDSB];
    int blk = blockIdx.x;
    if (blk < gemmBlocks) {
        gemm_body(As, Bs, A, B, C, M, N, K, blk / nby, blk % nby,
                  att_s, att_d, sout, dout, H);
    } else {
        int e = (blk - gemmBlocks) * 256 + threadIdx.x;
        if (e < E) {
            int pos = atomicAdd(&cursor[edst[e]], 1);
            srcs[pos] = esrc[e];
        }
    }
}

// ---------------- plain GEMM kernel (layer 2) ----------------
__global__ __launch_bounds__(256) void gemm_k(const ushort* __restrict__ A,
                                              const ushort* __restrict__ B,
                                              ushort* __restrict__ C,
                                              int M, int N, int K,
                                              const float* __restrict__ att_s,
                                              const float* __restrict__ att_d,
                                              float* __restrict__ sout,
                                              float* __restrict__ dout, int H,
                                              int nby) {
    __shared__ ushort As[128 * LDSB];
    __shared__ ushort Bs[128 * LDSB];
    gemm_body(As, Bs, A, B, C, M, N, K, blockIdx.x / nby, blockIdx.x % nby,
              att_s, att_d, sout, dout, H);
}

// ---------------- CSR scan + out prefill (out = b_out per graph) ----------
__global__ __launch_bounds__(1024) void scan_offsets(const int* cnt, int* row_start,
                                                     int* cursor, int N,
                                                     const float* __restrict__ b_out,
                                                     float* __restrict__ out) {
    __shared__ int sm[1024];
    int t = threadIdx.x;
    if (t < 512) out[t] = b_out[t & 1];
    int per = (N + 1023) / 1024;
    int beg = t * per;
    int end = beg + per; if (end > N) end = N;
    int sum = 0;
    for (int i = beg; i < end; ++i) sum += cnt[i];
    sm[t] = sum;
    __syncthreads();
    for (int off = 1; off < 1024; off <<= 1) {
        int add = (t >= off) ? sm[t - off] : 0;
        __syncthreads();
        sm[t] += add;
        __syncthreads();
    }
    int run = sm[t] - sum;
    for (int i = beg; i < end; ++i) {
        int c = cnt[i];
        row_start[i] = run;
        cursor[i] = run;
        run += c;
    }
    if (t == 1023) row_start[N] = run;
}

// -------- Layer-1 softmax-aggregate (R4 structure: 4-deep unroll + tail) -----
__global__ __launch_bounds__(256) void agg1(const ushort* __restrict__ h1,
                                            const float* __restrict__ a1s,
                                            const float* __restrict__ a1d,
                                            const int* __restrict__ row_start,
                                            const int* __restrict__ srcs,
                                            const float* __restrict__ b1,
                                            ushort* __restrict__ r1, int N) {
    int node = blockIdx.x * 4 + (threadIdx.x >> 6);
    if (node >= N) return;
    int lane = threadIdx.x & 63;
    int head = lane >> 3;
    int f0 = lane * 8;
    int pbeg = row_start[node], pend = row_start[node + 1];
    float ad = a1d[node * 8 + head];
    float es = a1s[node * 8 + head] + ad;
    es = es > 0.f ? es : NEG_SLOPE * es;
    float ex_self = __expf(es);
    float den = ex_self;
    float q[8];
    unpack8(*(const uint4*)(h1 + (size_t)node * 512 + f0), q);
    float acc[8];
#pragma unroll
    for (int j = 0; j < 8; ++j) acc[j] = ex_self * q[j];
    int p = pbeg;
    for (; p + 4 <= pend; p += 4) {
        int s0 = srcs[p + 0];
        int s1 = srcs[p + 1];
        int s2 = srcs[p + 2];
        int s3 = srcs[p + 3];
        uint4 u0 = *(const uint4*)(h1 + (size_t)s0 * 512 + f0);
        uint4 u1 = *(const uint4*)(h1 + (size_t)s1 * 512 + f0);
        uint4 u2 = *(const uint4*)(h1 + (size_t)s2 * 512 + f0);
        uint4 u3 = *(const uint4*)(h1 + (size_t)s3 * 512 + f0);
        float as0 = a1s[s0 * 8 + head];
        float as1 = a1s[s1 * 8 + head];
        float as2 = a1s[s2 * 8 + head];
        float as3 = a1s[s3 * 8 + head];
        float e0 = as0 + ad; e0 = e0 > 0.f ? e0 : NEG_SLOPE * e0;
        float e1 = as1 + ad; e1 = e1 > 0.f ? e1 : NEG_SLOPE * e1;
        float e2 = as2 + ad; e2 = e2 > 0.f ? e2 : NEG_SLOPE * e2;
        float e3 = as3 + ad; e3 = e3 > 0.f ? e3 : NEG_SLOPE * e3;
        float x0 = __expf(e0), x1 = __expf(e1), x2 = __expf(e2), x3 = __expf(e3);
        den += (x0 + x1) + (x2 + x3);
        float v[8];
        unpack8(u0, v);
#pragma unroll
        for (int j = 0; j < 8; ++j) acc[j] += x0 * v[j];
        unpack8(u1, v);
#pragma unroll
        for (int j = 0; j < 8; ++j) acc[j] += x1 * v[j];
        unpack8(u2, v);
#pragma unroll
        for (int j = 0; j < 8; ++j) acc[j] += x2 * v[j];
        unpack8(u3, v);
#pragma unroll
        for (int j = 0; j < 8; ++j) acc[j] += x3 * v[j];
    }
    for (; p < pend; ++p) {
        int s = srcs[p];
        float e = a1s[s * 8 + head] + ad;
        e = e > 0.f ? e : NEG_SLOPE * e;
        float ex = __expf(e);
        den += ex;
        float v[8];
        unpack8(*(const uint4*)(h1 + (size_t)s * 512 + f0), v);
#pragma unroll
        for (int j = 0; j < 8; ++j) acc[j] += ex * v[j];
    }
    float rden = 1.0f / (den + 1e-16f);
    const float4* bp = (const float4*)(b1 + f0);
    float4 b0 = bp[0], b1v = bp[1];
    float o[8];
    o[0] = fmaxf(acc[0] * rden + b0.x, 0.f);
    o[1] = fmaxf(acc[1] * rden + b0.y, 0.f);
    o[2] = fmaxf(acc[2] * rden + b0.z, 0.f);
    o[3] = fmaxf(acc[3] * rden + b0.w, 0.f);
    o[4] = fmaxf(acc[4] * rden + b1v.x, 0.f);
    o[5] = fmaxf(acc[5] * rden + b1v.y, 0.f);
    o[6] = fmaxf(acc[6] * rden + b1v.z, 0.f);
    o[7] = fmaxf(acc[7] * rden + b1v.w, 0.f);
    uint4 ov;
    ov.x = pack2(o[0], o[1]); ov.y = pack2(o[2], o[3]);
    ov.z = pack2(o[4], o[5]); ov.w = pack2(o[6], o[7]);
    *(uint4*)(r1 + (size_t)node * 512 + f0) = ov;
}

// -------- Layer-2 aggregate + pooling + output GEMM, all fused ---------------
// 2 nodes/wave (32 lanes, 4 feats/lane), masked 8-deep edge unroll (64 lines
// in flight/wave). Per node: r2 row in regs -> w_n = attn*mask and the two
// W_out dots reduced across 32 lanes -> 2 atomicAdds into out[g] (prefilled
// with b_out). pooled buffer + final_kernel eliminated.
__global__ __launch_bounds__(256) void agg2out(const ushort* __restrict__ h2,
                                               const float* __restrict__ a2s,
                                               const float* __restrict__ a2d,
                                               const int* __restrict__ row_start,
                                               const int* __restrict__ srcs,
                                               const float* __restrict__ b2,
                                               const int* __restrict__ batch,
                                               const float* __restrict__ w_attn,
                                               const float* __restrict__ b_attn,
                                               const float* __restrict__ w_mask,
                                               const float* __restrict__ b_mask,
                                               const float* __restrict__ W_out,
                                               float* __restrict__ out, int N) {
    int node = blockIdx.x * 8 + (threadIdx.x >> 5);
    if (node >= N) return;
    int sub = threadIdx.x & 31;
    int f0 = sub * 4;
    int pbeg = row_start[node], pend = row_start[node + 1];
    float ad = a2d[node];
    float es = a2s[node] + ad;
    es = es > 0.f ? es : NEG_SLOPE * es;
    float ex_self = __expf(es);
    float den = ex_self;
    float q[4];
    unpack4(*(const uint2*)(h2 + (size_t)node * 128 + f0), q);
    float acc[4];
#pragma unroll
    for (int j = 0; j < 4; ++j) acc[j] = ex_self * q[j];
    for (int p = pbeg; p < pend; p += 8) {
        int sidx[8]; bool okb[8];
#pragma unroll
        for (int k = 0; k < 8; ++k) {
            int pk = p + k;
            okb[k] = pk < pend;
            sidx[k] = srcs[okb[k] ? pk : pbeg];
        }
        uint2 u[8];
#pragma unroll
        for (int k = 0; k < 8; ++k)
            u[k] = *(const uint2*)(h2 + (size_t)sidx[k] * 128 + f0);
        float sc[8];
#pragma unroll
        for (int k = 0; k < 8; ++k) sc[k] = a2s[sidx[k]];
#pragma unroll
        for (int k = 0; k < 8; ++k) {
            float e = sc[k] + ad;
            e = e > 0.f ? e : NEG_SLOPE * e;
            float xk = okb[k] ? __expf(e) : 0.f;
            den += xk;
            float v[4];
            unpack4(u[k], v);
#pragma unroll
            for (int j = 0; j < 4; ++j) acc[j] += xk * v[j];
        }
    }
    float rden = 1.0f / (den + 1e-16f);
    float4 bv = *(const float4*)(b2 + f0);
    float4 o;
    o.x = fmaxf(acc[0] * rden + bv.x, 0.f);
    o.y = fmaxf(acc[1] * rden + bv.y, 0.f);
    o.z = fmaxf(acc[2] * rden + bv.z, 0.f);
    o.w = fmaxf(acc[3] * rden + bv.w, 0.f);
    // ---- fused pooling + output projection ----
    float4 wa = *(const float4*)(w_attn + f0);
    float4 wm = *(const float4*)(w_mask + f0);
    float4 w0 = *(const float4*)(W_out + f0);        // W_out row 0
    float4 w1 = *(const float4*)(W_out + 128 + f0);  // W_out row 1
    float pa = o.x * wa.x + o.y * wa.y + o.z * wa.z + o.w * wa.w;
    float pm = o.x * wm.x + o.y * wm.y + o.z * wm.z + o.w * wm.w;
    float d0 = o.x * w0.x + o.y * w0.y + o.z * w0.z + o.w * w0.w;
    float d1 = o.x * w1.x + o.y * w1.y + o.z * w1.z + o.w * w1.w;
#pragma unroll
    for (int off = 1; off < 32; off <<= 1) {
        pa += __shfl_xor(pa, off);
        pm += __shfl_xor(pm, off);
        d0 += __shfl_xor(d0, off);
        d1 += __shfl_xor(d1, off);
    }
    if (sub == 0) {
        float attn = pa + b_attn[0];
        float mask = 1.0f / (1.0f + __expf(-(pm + b_mask[0])));
        float w = attn * mask;
        int g = batch[node];
        atomicAdd(&out[g * 2 + 0], w * d0);
        atomicAdd(&out[g * 2 + 1], w * d1);
    }
}

extern "C" void kernel_launch(void* const* d_in, const int* in_sizes, int n_in,
                              void* d_out, int out_size, void* d_ws, size_t ws_size,
                              hipStream_t stream) {
    const float* x        = (const float*)d_in[0];
    const int* edge_index = (const int*)d_in[1];
    const int* batch      = (const int*)d_in[2];
    const float* W1       = (const float*)d_in[3];
    const float* att_src1 = (const float*)d_in[4];
    const float* att_dst1 = (const float*)d_in[5];
    const float* b1       = (const float*)d_in[6];
    const float* W2       = (const float*)d_in[7];
    const float* att_src2 = (const float*)d_in[8];
    const float* att_dst2 = (const float*)d_in[9];
    const float* b2       = (const float*)d_in[10];
    const float* w_attn   = (const float*)d_in[11];
    const float* b_attn   = (const float*)d_in[12];
    const float* w_mask   = (const float*)d_in[13];
    const float* b_mask   = (const float*)d_in[14];
    const float* W_out    = (const float*)d_in[15];
    const float* b_out    = (const float*)d_in[16];
    float* out = (float*)d_out;

    int N = in_sizes[0] / 128;
    int E = in_sizes[1] / 2;
    const int* esrc = edge_index;
    const int* edst = edge_index + E;

    char* ws = (char*)d_ws;
    size_t off = 0;
    auto alloc = [&](size_t bytes) {
        void* p = ws + off;
        off = (off + bytes + 255) & ~(size_t)255;
        return p;
    };
    ushort* h1       = (ushort*)alloc((size_t)N * 512 * 2);   // bf16
    ushort* r1       = (ushort*)alloc((size_t)N * 512 * 2);   // bf16
    ushort* h2       = (ushort*)alloc((size_t)N * 128 * 2);   // bf16
    ushort* xb       = (ushort*)alloc((size_t)N * 128 * 2);   // bf16 x
    ushort* w1b      = (ushort*)alloc((size_t)512 * 128 * 2);
    ushort* w2b      = (ushort*)alloc((size_t)128 * 512 * 2);
    float*  a1s      = (float*)alloc((size_t)N * 8 * 4);
    float*  a1d      = (float*)alloc((size_t)N * 8 * 4);
    int*    row_start= (int*)alloc((size_t)(N + 1) * 4);
    int*    srcs     = (int*)alloc((size_t)E * 4);
    // zero-init region: cursor, a2s, a2d (contiguous, one memset)
    int*    cursor   = (int*)alloc((size_t)N * 4);
    float*  a2s      = (float*)alloc((size_t)N * 4);
    float*  a2d      = (float*)alloc((size_t)N * 4);
    size_t zspan = (size_t)((char*)(a2d + N) - (char*)cursor);
    hipMemsetAsync(cursor, 0, zspan, stream);

    dim3 b256(256);
    // prep: converts + edge count in one launch
    int nx4 = N * 128 / 4;
    int nw4 = 512 * 128 / 4;
    int cvtBlocks = (nx4 + 2 * nw4 + 255) / 256;
    int cntBlocks = (E + 255) / 256;
    prep<<<cvtBlocks + cntBlocks, b256, 0, stream>>>(x, xb, nx4, W1, w1b, nw4,
                                                     W2, w2b, nw4, cvtBlocks,
                                                     edst, cursor, E);
    scan_offsets<<<1, 1024, 0, stream>>>(cursor, row_start, cursor, N, b_out, out);
    // gemm1 (fused scores H=8) + fill_edges in one launch
    int g1Blocks = ((N + 127) / 128) * 4;
    g1f<<<g1Blocks + cntBlocks, b256, 0, stream>>>(xb, w1b, h1, N, 512, 128,
                                                   att_src1, att_dst1, a1s, a1d, 8,
                                                   g1Blocks, 4,
                                                   esrc, edst, cursor, srcs, E);
    agg1<<<(N + 3) / 4, b256, 0, stream>>>(h1, a1s, a1d, row_start, srcs, b1, r1, N);
    // layer 2 gemm (fused scores H=1, atomics into zeroed a2s/a2d)
    gemm_k<<<(N + 127) / 128, b256, 0, stream>>>(r1, w2b, h2, N, 128, 512,
                                                 att_src2, att_dst2, a2s, a2d, 1, 1);
    // layer 2 aggregate + pooling + output projection fused
    agg2out<<<(N + 7) / 8, b256, 0, stream>>>(h2, a2s, a2d, row_start, srcs, b2,
                                              batch, w_attn, b_attn, w_mask, b_mask,
                                              W_out, out, N);
}